// Round 8
// baseline (963.189 us; speedup 1.0000x reference)
//
#include <hip/hip_runtime.h>
#include <hip/hip_bf16.h>
#include <hip/hip_fp16.h>

#define N_NODES 50000
#define N_EDGES 800000
#define DIM 64
#define ODIM 32
#define N_GRAPHS 512
#define GEMM_BLOCKS ((N_NODES + 31) / 32) // 1563
#define EPT 5                             // edges per thread (exact: 800000 = 625*256*5)
#define EDGE_BLOCKS (N_EDGES / (256 * EPT))  // 625
#define EDGE_STRIDE (EDGE_BLOCKS * 256)      // 160000

// LDS counting-sort geometry: 125 edge-chunks x 4 node-ranges.
#define NCH 125
#define CHUNK (N_EDGES / NCH)             // 6400
#define SWEEPS (CHUNK / 256)              // 25
#define UNR 5
#define NR 4
#define NRANGE (N_NODES / NR)             // 12500 nodes per range
#define HCOLS (NRANGE / 2)                // 6250 packed-u32 cols (2 nodes/u32)
#define NHB (NCH * NR)                    // 500 hist blocks
#define NCOLS_TOTAL (NR * HCOLS)          // 25000
#define SCAN_NB2 ((N_NODES + 511) / 512)  // 98 (512 nodes per scan block)

#define AGG_BLOCKS (N_NODES / 16)         // 3125

__device__ __forceinline__ float bflo(unsigned int u) { return __uint_as_float(u << 16); }
__device__ __forceinline__ float bfhi(unsigned int u) { return __uint_as_float(u & 0xffff0000u); }
__device__ __forceinline__ float h16tof(unsigned int hbits) {
    return __half2float(__ushort_as_half((unsigned short)hbits));
}

// ---- fused: LDS-histogram count (zero global atomics) + layer-1 GEMM ----
// (r5 structure restored: persistent/spin-barrier topology regressed 2 rounds
// running — r6 585us, r7 724us vs r5 213us — pre-commit says revert.)

__global__ __launch_bounds__(256) void prep_gemm(const int* __restrict__ dst,
                                                 unsigned short* __restrict__ rank,
                                                 unsigned int* __restrict__ cnt_blocks,
                                                 const float* __restrict__ X,
                                                 const float* __restrict__ W,
                                                 __hip_bfloat16* __restrict__ Ybf) {
    __shared__ unsigned int smem[HCOLS];   // 25KB; GEMM reuses as float Ws[4096] (16KB)
    if (blockIdx.x < NHB) {
        unsigned int* hist = smem;
        int c = blockIdx.x >> 2, r = blockIdx.x & 3;
        for (int i = threadIdx.x; i < HCOLS; i += 256) hist[i] = 0;
        __syncthreads();
        int lo = r * NRANGE;
        int base = c * CHUNK + threadIdx.x;
#pragma unroll 1
        for (int b = 0; b < SWEEPS / UNR; ++b) {
            int d[UNR];
#pragma unroll
            for (int u = 0; u < UNR; ++u)                 // 5 loads in flight
                d[u] = dst[base + (b * UNR + u) * 256];
#pragma unroll
            for (int u = 0; u < UNR; ++u) {
                unsigned int ld = (unsigned int)(d[u] - lo);
                if (ld < (unsigned int)NRANGE) {
                    unsigned int sh = (ld & 1u) * 16u;
                    unsigned int ret = atomicAdd(&hist[ld >> 1], 1u << sh);
                    rank[base + (b * UNR + u) * 256] = (unsigned short)((ret >> sh) & 0xffffu);
                }
            }
        }
        __syncthreads();
        unsigned int* out = cnt_blocks + (size_t)blockIdx.x * HCOLS;
        for (int i = threadIdx.x; i < HCOLS; i += 256) out[i] = hist[i];
        return;
    }
    // ---- GEMM part: h = X @ W (N x 64 @ 64 x 64), bf16 out ----
    int bid = blockIdx.x - NHB;
    float* Ws = (float*)smem;
    for (int i = threadIdx.x; i < 64 * 64; i += 256) Ws[i] = W[i];
    __syncthreads();
    int wave = threadIdx.x >> 6;
    int j    = threadIdx.x & 63;
    int row0 = (bid * 4 + wave) * 8;
    if (row0 >= N_NODES) return;
    float acc[8] = {0,0,0,0,0,0,0,0};
    const float* x0 = X + (size_t)row0 * DIM;   // wave-uniform
    int nr = (row0 + 8 <= N_NODES) ? 8 : (N_NODES - row0);
    if (nr == 8) {
#pragma unroll
        for (int k4 = 0; k4 < 16; ++k4) {
            float w0 = Ws[(4 * k4 + 0) * 64 + j];
            float w1 = Ws[(4 * k4 + 1) * 64 + j];
            float w2 = Ws[(4 * k4 + 2) * 64 + j];
            float w3 = Ws[(4 * k4 + 3) * 64 + j];
#pragma unroll
            for (int r = 0; r < 8; ++r) {
                float4 x4 = *(const float4*)&x0[r * DIM + k4 * 4];
                acc[r] = fmaf(x4.x, w0, acc[r]);
                acc[r] = fmaf(x4.y, w1, acc[r]);
                acc[r] = fmaf(x4.z, w2, acc[r]);
                acc[r] = fmaf(x4.w, w3, acc[r]);
            }
        }
    } else {
        for (int k4 = 0; k4 < 16; ++k4) {
            float w0 = Ws[(4 * k4 + 0) * 64 + j];
            float w1 = Ws[(4 * k4 + 1) * 64 + j];
            float w2 = Ws[(4 * k4 + 2) * 64 + j];
            float w3 = Ws[(4 * k4 + 3) * 64 + j];
            for (int r = 0; r < nr; ++r) {
                float4 x4 = *(const float4*)&x0[r * DIM + k4 * 4];
                acc[r] = fmaf(x4.x, w0, acc[r]);
                acc[r] = fmaf(x4.y, w1, acc[r]);
                acc[r] = fmaf(x4.z, w2, acc[r]);
                acc[r] = fmaf(x4.w, w3, acc[r]);
            }
        }
    }
    for (int r = 0; r < nr; ++r)
        Ybf[(size_t)(row0 + r) * DIM + j] = __float2bfloat16(acc[r]);
}

// ---- column scan + fused block-sum reduction + sums/done zeroing ----

__global__ __launch_bounds__(256) void colscan(const unsigned int* __restrict__ cnt_blocks,
                                               unsigned int* __restrict__ blockbase,
                                               int* __restrict__ deg,
                                               int* __restrict__ blocksum,
                                               float* __restrict__ sums,
                                               int* __restrict__ done) {
    __shared__ int ws[4];
    int q = blockIdx.x * 256 + threadIdx.x;
    int d0 = 0, d1 = 0;
    if (q < NCOLS_TOTAL) {
        int r = q / HCOLS, col = q % HCOLS;
        unsigned int run = 0;
#pragma unroll 5
        for (int c = 0; c < NCH; ++c) {
            size_t idx = (size_t)(c * NR + r) * HCOLS + col;
            unsigned int v = cnt_blocks[idx];
            blockbase[idx] = run;      // exclusive prefix (packed u16x2)
            run += v;
        }
        d0 = (int)(run & 0xffffu);
        d1 = (int)(run >> 16);
        deg[2 * q]     = d0;
        deg[2 * q + 1] = d1;
    }
    int v = d0 + d1;
    for (int d = 32; d > 0; d >>= 1) v += __shfl_down(v, d, 64);
    int lane = threadIdx.x & 63, wid = threadIdx.x >> 6;
    if (lane == 0) ws[wid] = v;
    __syncthreads();
    if (threadIdx.x == 0) blocksum[blockIdx.x] = ws[0] + ws[1] + ws[2] + ws[3];
    if (blockIdx.x == 0) {
        for (int i = threadIdx.x; i < N_GRAPHS * DIM; i += 256) sums[i] = 0.f;
        if (threadIdx.x == 0) *done = 0;   // re-zeroed every graph replay
    }
}

// ---- final scan: 512 nodes/block (2/thread) ----

__global__ __launch_bounds__(256) void scan_p3(const int* __restrict__ deg,
                                               const int* __restrict__ blocksum,
                                               int* __restrict__ off,
                                               float* __restrict__ inv_sqrt,
                                               float* __restrict__ invdeg) {
    __shared__ int wtot[4];
    __shared__ int bb[SCAN_NB2 + 1];
    {
        int t = threadIdx.x;
        int v = (t < SCAN_NB2) ? blocksum[t] : 0;
        int lane = t & 63, wid = t >> 6;
        int incl = v;
        for (int d = 1; d < 64; d <<= 1) {
            int u = __shfl_up(incl, d, 64);
            if (lane >= d) incl += u;
        }
        if (lane == 63) wtot[wid] = incl;
        __syncthreads();
        int base = 0;
        for (int w = 0; w < wid; ++w) base += wtot[w];
        incl += base;
        if (t <= SCAN_NB2) bb[t] = incl - v;   // exclusive; bb[SCAN_NB2] = total
        __syncthreads();
    }
    if (blockIdx.x == 0 && threadIdx.x == 0) off[N_NODES] = bb[SCAN_NB2];
    __syncthreads();

    int n = blockIdx.x * 512 + 2 * threadIdx.x;
    int d0 = 0, d1 = 0;
    if (n < N_NODES) { int2 dd = *(const int2*)&deg[n]; d0 = dd.x; d1 = dd.y; }
    int v = d0 + d1;
    int lane = threadIdx.x & 63, wid = threadIdx.x >> 6;
    int incl = v;
    for (int d = 1; d < 64; d <<= 1) {
        int u = __shfl_up(incl, d, 64);
        if (lane >= d) incl += u;
    }
    if (lane == 63) wtot[wid] = incl;
    __syncthreads();
    int base = bb[blockIdx.x];
    for (int w = 0; w < wid; ++w) base += wtot[w];
    int excl = base + incl - v;
    if (n < N_NODES) {
        off[n]     = excl;
        off[n + 1] = excl + d0;
        float f0 = (float)(d0 + 1), f1 = (float)(d1 + 1);   // +1: self-loop
        inv_sqrt[n]     = rsqrtf(f0);
        inv_sqrt[n + 1] = rsqrtf(f1);
        invdeg[n]       = 1.0f / f0;
        invdeg[n + 1]   = 1.0f / f1;
    }
}

// ---- atomic-free scatter: pos = off[d] + blockbase(chunk,d) + rank ----
// Edge record: src (u16) | half(inv_sqrt[src]) << 16; dst-side isq applied
// per node in the aggs.

__global__ __launch_bounds__(256) void scatter_edges(const int* __restrict__ src,
                                                     const int* __restrict__ dst,
                                                     const unsigned short* __restrict__ rank,
                                                     const int* __restrict__ off,
                                                     const unsigned int* __restrict__ blockbase,
                                                     const float* __restrict__ inv_sqrt,
                                                     unsigned int* __restrict__ edges) {
    int t = blockIdx.x * 256 + threadIdx.x;
    int d[EPT], s[EPT];
    unsigned short rk[EPT];
#pragma unroll
    for (int i = 0; i < EPT; ++i) d[i] = dst[t + i * EDGE_STRIDE];
#pragma unroll
    for (int i = 0; i < EPT; ++i) s[i] = src[t + i * EDGE_STRIDE];
#pragma unroll
    for (int i = 0; i < EPT; ++i) rk[i] = rank[t + i * EDGE_STRIDE];
    int pos[EPT];
    float w[EPT];
#pragma unroll
    for (int i = 0; i < EPT; ++i) {
        int e = t + i * EDGE_STRIDE;
        int c = e / CHUNK;
        int r = d[i] / NRANGE;
        int ld = d[i] - r * NRANGE;
        unsigned int bb = blockbase[(size_t)(c * NR + r) * HCOLS + (ld >> 1)];
        int base16 = (int)((bb >> ((ld & 1) * 16)) & 0xffffu);
        pos[i] = off[d[i]] + base16 + (int)rk[i];
    }
#pragma unroll
    for (int i = 0; i < EPT; ++i) w[i] = inv_sqrt[s[i]];
#pragma unroll
    for (int i = 0; i < EPT; ++i) {
        unsigned short hw = __half_as_ushort(__float2half(w[i]));
        edges[pos[i]] = (unsigned int)s[i] | ((unsigned int)hw << 16);
    }
}

// ---- half-wave packed merged-stream gather for 4 consecutive nodes ----
// Depth-3 pipeline (r5-identical).
__device__ __forceinline__ void gather4_packed(
    const unsigned int* __restrict__ H2,
    const unsigned int* __restrict__ edges,
    int e0, int b1, int b2, int b3, int e4, int m, int h,
    float (&aLo)[4], float (&aHi)[4])
{
    int k = e0;
    int B = (e4 - e0) >> 3;

    unsigned int E0[4], E1[4], E2[4];
    unsigned int U0[4], U1[4];

    auto ld4 = [&](unsigned int* E, int kb) {
#pragma unroll
        for (int i = 0; i < 4; ++i) E[i] = edges[kb + 2 * i + h];
    };
    auto gt4 = [&](unsigned int* U, const unsigned int* E) {
#pragma unroll
        for (int i = 0; i < 4; ++i)
            U[i] = H2[(size_t)(E[i] & 0xffffu) * 32 + m];
    };
    auto consume = [&](const unsigned int* E, const unsigned int* U, int kb) {
        int selA = (kb >= b1) + (kb >= b2) + (kb >= b3);
        int selB = (kb + 7 >= b1) + (kb + 7 >= b2) + (kb + 7 >= b3);
        if (selA == selB) {                 // whole batch in one node (common)
            float sLo = 0.f, sHi = 0.f;
#pragma unroll
            for (int i = 0; i < 4; ++i) {
                float w = h16tof(E[i] >> 16);
                sLo = fmaf(bflo(U[i]), w, sLo);
                sHi = fmaf(bfhi(U[i]), w, sHi);
            }
            if      (selA == 0) { aLo[0] += sLo; aHi[0] += sHi; }
            else if (selA == 1) { aLo[1] += sLo; aHi[1] += sHi; }
            else if (selA == 2) { aLo[2] += sLo; aHi[2] += sHi; }
            else                { aLo[3] += sLo; aHi[3] += sHi; }
        } else {                            // boundary batch: per-edge select
#pragma unroll
            for (int i = 0; i < 4; ++i) {
                int kk = kb + 2 * i + h;
                float w = h16tof(E[i] >> 16);
                float pLo = bflo(U[i]) * w;
                float pHi = bfhi(U[i]) * w;
                int sel = (kk >= b1) + (kk >= b2) + (kk >= b3);
                aLo[0] += (sel == 0) ? pLo : 0.f;  aHi[0] += (sel == 0) ? pHi : 0.f;
                aLo[1] += (sel == 1) ? pLo : 0.f;  aHi[1] += (sel == 1) ? pHi : 0.f;
                aLo[2] += (sel == 2) ? pLo : 0.f;  aHi[2] += (sel == 2) ? pHi : 0.f;
                aLo[3] += (sel == 3) ? pLo : 0.f;  aHi[3] += (sel == 3) ? pHi : 0.f;
            }
        }
    };

    if (B >= 3) {
        ld4(E0, k);      gt4(U0, E0);
        ld4(E1, k + 8);  gt4(U1, E1);
        ld4(E2, k + 16);
        for (int b = 0; b < B - 3; ++b) {
            unsigned int U2[4];
            gt4(U2, E2);              // batch b+2 gathers in flight
            unsigned int E3[4];
            ld4(E3, k + 24);          // batch b+3 edge loads in flight
            consume(E0, U0, k);       // waits only on batch b gathers
#pragma unroll
            for (int i = 0; i < 4; ++i) {
                E0[i] = E1[i]; U0[i] = U1[i];
                E1[i] = E2[i]; U1[i] = U2[i];
                E2[i] = E3[i];
            }
            k += 8;
        }
        {
            unsigned int U2[4];
            gt4(U2, E2);
            consume(E0, U0, k); k += 8;
            consume(E1, U1, k); k += 8;
            consume(E2, U2, k); k += 8;
        }
    } else if (B == 2) {
        ld4(E0, k);     gt4(U0, E0);
        ld4(E1, k + 8); gt4(U1, E1);
        consume(E0, U0, k); k += 8;
        consume(E1, U1, k); k += 8;
    } else if (B == 1) {
        ld4(E0, k); gt4(U0, E0); consume(E0, U0, k); k += 8;
    }
    for (; k < e4; ++k) {
        if ((k & 1) == h) {       // split tail edges between halves
            unsigned int e = edges[k];
            unsigned int u = H2[(size_t)(e & 0xffffu) * 32 + m];
            float w = h16tof(e >> 16);
            float pLo = bflo(u) * w;
            float pHi = bfhi(u) * w;
            int sel = (k >= b1) + (k >= b2) + (k >= b3);
            aLo[0] += (sel == 0) ? pLo : 0.f;  aHi[0] += (sel == 0) ? pHi : 0.f;
            aLo[1] += (sel == 1) ? pLo : 0.f;  aHi[1] += (sel == 1) ? pHi : 0.f;
            aLo[2] += (sel == 2) ? pLo : 0.f;  aHi[2] += (sel == 2) ? pHi : 0.f;
            aLo[3] += (sel == 3) ? pLo : 0.f;  aHi[3] += (sel == 3) ? pHi : 0.f;
        }
    }
}

// ---- fused: layer-1 aggregate (+bias1, relu) THEN layer-2 gemm (@W2) ----

__global__ __launch_bounds__(256) void agg_gemm(const __hip_bfloat16* __restrict__ Hbf,
                                                const int* __restrict__ off,
                                                const unsigned int* __restrict__ edges,
                                                const float* __restrict__ inv_sqrt,
                                                const float* __restrict__ invdeg,
                                                const float* __restrict__ bias,
                                                const float* __restrict__ W2,
                                                __hip_bfloat16* __restrict__ Ybf2) {
    __shared__ float Ws[64 * 64];
    __shared__ float rowbuf[4][4][64];   // [wave][r][j]
    for (int i = threadIdx.x; i < 64 * 64; i += 256) Ws[i] = W2[i];
    __syncthreads();
    const unsigned int* H2 = (const unsigned int*)Hbf;
    int wave = threadIdx.x >> 6;
    int j    = threadIdx.x & 63;
    int m = j & 31, h = j >> 5;
    int n0   = (blockIdx.x * 4 + wave) * 4;   // N_NODES = 16*3125: exact
    int e0 = off[n0], b1v = off[n0 + 1], b2v = off[n0 + 2], b3v = off[n0 + 3], e4 = off[n0 + 4];
    float aLo[4] = {0.f, 0.f, 0.f, 0.f};
    float aHi[4] = {0.f, 0.f, 0.f, 0.f};
    gather4_packed(H2, edges, e0, b1v, b2v, b3v, e4, m, h, aLo, aHi);
    float bLo = bias[2 * m], bHi = bias[2 * m + 1];
#pragma unroll
    for (int r = 0; r < 4; ++r) {
        aLo[r] += __shfl_xor(aLo[r], 32);
        aHi[r] += __shfl_xor(aHi[r], 32);
        float isq = inv_sqrt[n0 + r];
        aLo[r] *= isq;
        aHi[r] *= isq;
        unsigned int u = H2[(size_t)(n0 + r) * 32 + m];   // self row
        float iv = invdeg[n0 + r];
        float vLo = fmaf(bflo(u), iv, aLo[r]) + bLo;
        float vHi = fmaf(bfhi(u), iv, aHi[r]) + bHi;
        if (h == 0) {
            rowbuf[wave][r][2 * m]     = fmaxf(vLo, 0.f);
            rowbuf[wave][r][2 * m + 1] = fmaxf(vHi, 0.f);
        }
    }
    // same-wave LDS write->read: compiler inserts lgkmcnt wait; no barrier needed
    float acc2[4] = {0.f, 0.f, 0.f, 0.f};
#pragma unroll
    for (int k4 = 0; k4 < 16; ++k4) {
        float w0 = Ws[(4 * k4 + 0) * 64 + j];
        float w1 = Ws[(4 * k4 + 1) * 64 + j];
        float w2 = Ws[(4 * k4 + 2) * 64 + j];
        float w3 = Ws[(4 * k4 + 3) * 64 + j];
#pragma unroll
        for (int r = 0; r < 4; ++r) {
            float4 h4 = *(const float4*)&rowbuf[wave][r][k4 * 4];  // broadcast: free
            acc2[r] = fmaf(h4.x, w0, acc2[r]);
            acc2[r] = fmaf(h4.y, w1, acc2[r]);
            acc2[r] = fmaf(h4.z, w2, acc2[r]);
            acc2[r] = fmaf(h4.w, w3, acc2[r]);
        }
    }
#pragma unroll
    for (int r = 0; r < 4; ++r)
        Ybf2[(size_t)(n0 + r) * DIM + j] = __float2bfloat16(acc2[r]);
}

// ---- layer-2 aggregate (+bias2, relu) + mean-pool + last-block FC ----
// After pool atomics, each block's thread0 does an acq-rel fetch_add on done;
// the LAST block (fetch_add returns AGG_BLOCKS-1) computes the FC for all
// graphs. No spinning: canonical threadfence-reduction pattern.
// __syncthreads before the fetch_add implies vmcnt(0) drain, so this block's
// atomics are at the coherence point; the release makes them visible; the
// acquiring last block then reads converged sums.

__global__ __launch_bounds__(256) void agg_pool_fc(const __hip_bfloat16* __restrict__ Hbf,
                                                   const int* __restrict__ off,
                                                   const unsigned int* __restrict__ edges,
                                                   const float* __restrict__ inv_sqrt,
                                                   const float* __restrict__ invdeg,
                                                   const float* __restrict__ bias,
                                                   const int* __restrict__ batch,
                                                   float* __restrict__ sums,
                                                   const float* __restrict__ fcW,
                                                   const float* __restrict__ fcb,
                                                   float* __restrict__ out,
                                                   int* __restrict__ done) {
    __shared__ float mean[4][64];
    __shared__ int lastflag;
    const unsigned int* H2 = (const unsigned int*)Hbf;
    int wave = threadIdx.x >> 6;
    int j    = threadIdx.x & 63;
    int m = j & 31, h = j >> 5;
    int n0   = (blockIdx.x * 4 + wave) * 4;   // exact
    int e0 = off[n0], b1v = off[n0 + 1], b2v = off[n0 + 2], b3v = off[n0 + 3], e4 = off[n0 + 4];
    float aLo[4] = {0.f, 0.f, 0.f, 0.f};
    float aHi[4] = {0.f, 0.f, 0.f, 0.f};
    gather4_packed(H2, edges, e0, b1v, b2v, b3v, e4, m, h, aLo, aHi);
    float bLo = bias[2 * m], bHi = bias[2 * m + 1];
    float vLo[4], vHi[4];
#pragma unroll
    for (int r = 0; r < 4; ++r) {
        aLo[r] += __shfl_xor(aLo[r], 32);
        aHi[r] += __shfl_xor(aHi[r], 32);
        float isq = inv_sqrt[n0 + r];
        aLo[r] *= isq;
        aHi[r] *= isq;
        unsigned int u = H2[(size_t)(n0 + r) * 32 + m];
        float iv = invdeg[n0 + r];
        vLo[r] = fmaxf(fmaf(bflo(u), iv, aLo[r]) + bLo, 0.f);
        vHi[r] = fmaxf(fmaf(bfhi(u), iv, aHi[r]) + bHi, 0.f);
    }
    if (h == 0) {
        int g0 = batch[n0], g3 = batch[n0 + 3];
        if (g0 == g3) {
            atomicAdd(&sums[g0 * DIM + 2 * m],     (vLo[0] + vLo[1]) + (vLo[2] + vLo[3]));
            atomicAdd(&sums[g0 * DIM + 2 * m + 1], (vHi[0] + vHi[1]) + (vHi[2] + vHi[3]));
        } else {
#pragma unroll
            for (int r = 0; r < 4; ++r) {
                int g = batch[n0 + r];
                atomicAdd(&sums[g * DIM + 2 * m],     vLo[r]);
                atomicAdd(&sums[g * DIM + 2 * m + 1], vHi[r]);
            }
        }
    }
    // ---- last-block FC ----
    __syncthreads();                       // implies vmcnt(0): atomics at coherence point
    if (threadIdx.x == 0) {
        int prev = __hip_atomic_fetch_add(done, 1, __ATOMIC_ACQ_REL, __HIP_MEMORY_SCOPE_AGENT);
        lastflag = (prev == AGG_BLOCKS - 1);
        if (lastflag) __threadfence();     // acquire: invalidate caches before sums reads
    }
    __syncthreads();
    if (!lastflag) return;
    // this block alone: FC for all graphs; wave w handles graphs w, w+4, ...
    for (int g = wave; g < N_GRAPHS; g += 4) {
        int lo = 0, hi = N_NODES;
        while (lo < hi) { int mid = (lo + hi) >> 1; if (batch[mid] < g) lo = mid + 1; else hi = mid; }
        int start = lo;
        hi = N_NODES;
        while (lo < hi) { int mid = (lo + hi) >> 1; if (batch[mid] < g + 1) lo = mid + 1; else hi = mid; }
        int end = lo;
        float inv = 1.0f / fmaxf((float)(end - start), 1.0f);
        mean[wave][j] = sums[g * DIM + j] * inv;   // same-wave LDS, no barrier
        if (j < ODIM) {
            float a = fcb[j];
#pragma unroll
            for (int k = 0; k < DIM; ++k) a = fmaf(mean[wave][k], fcW[k * ODIM + j], a);
            out[g * ODIM + j] = a;
        }
    }
}

extern "C" void kernel_launch(void* const* d_in, const int* in_sizes, int n_in,
                              void* d_out, int out_size, void* d_ws, size_t ws_size,
                              hipStream_t stream) {
    const float* x    = (const float*)d_in[0];
    const float* W1   = (const float*)d_in[1];
    const float* b1   = (const float*)d_in[2];
    const float* W2   = (const float*)d_in[3];
    const float* b2   = (const float*)d_in[4];
    const float* fcW  = (const float*)d_in[5];
    const float* fcb  = (const float*)d_in[6];
    const int*   eidx = (const int*)d_in[7];
    const int*   batch= (const int*)d_in[8];
    const int* esrc = eidx;
    const int* edst = eidx + N_EDGES;
    float* out = (float*)d_out;

    char* ws = (char*)d_ws;
    size_t o = 0;
    auto alloc = [&](size_t bytes) {
        void* p = ws + o;
        o += (bytes + 255) & ~(size_t)255;
        return p;
    };
    float* sums     = (float*)alloc((size_t)N_GRAPHS * DIM * 4);   // zeroed by colscan block 0
    __hip_bfloat16* bf1 = (__hip_bfloat16*)alloc((size_t)N_NODES * DIM * 2);
    __hip_bfloat16* bf2 = (__hip_bfloat16*)alloc((size_t)N_NODES * DIM * 2);
    int*   deg      = (int*)  alloc((size_t)N_NODES * 4);
    int*   off      = (int*)  alloc((size_t)(N_NODES + 1) * 4);
    float* inv_sqrt = (float*)alloc((size_t)N_NODES * 4);
    float* invdeg   = (float*)alloc((size_t)N_NODES * 4);
    unsigned short* rank = (unsigned short*)alloc((size_t)N_EDGES * 2);
    unsigned int* edges = (unsigned int*)alloc((size_t)N_EDGES * 4);
    unsigned int* cnt_blocks = (unsigned int*)alloc((size_t)NHB * HCOLS * 4);  // 12.5MB
    unsigned int* blockbase  = (unsigned int*)alloc((size_t)NHB * HCOLS * 4);  // 12.5MB
    int*   blocksum = (int*)  alloc((size_t)SCAN_NB2 * 4);
    int*   done     = (int*)  alloc(sizeof(int));

    prep_gemm<<<NHB + GEMM_BLOCKS, 256, 0, stream>>>(edst, rank, cnt_blocks, x, W1, bf1);
    colscan<<<SCAN_NB2, 256, 0, stream>>>(cnt_blocks, blockbase, deg, blocksum, sums, done);
    scan_p3<<<SCAN_NB2, 256, 0, stream>>>(deg, blocksum, off, inv_sqrt, invdeg);
    scatter_edges<<<EDGE_BLOCKS, 256, 0, stream>>>(esrc, edst, rank, off, blockbase, inv_sqrt, edges);

    agg_gemm<<<AGG_BLOCKS, 256, 0, stream>>>(bf1, off, edges, inv_sqrt, invdeg, b1, W2, bf2);
    agg_pool_fc<<<AGG_BLOCKS, 256, 0, stream>>>(bf2, off, edges, inv_sqrt, invdeg, b2, batch,
                                                sums, fcW, fcb, out, done);
}

// Round 9
// 223.425 us; speedup vs baseline: 4.3110x; 4.3110x over previous
//
#include <hip/hip_runtime.h>
#include <hip/hip_bf16.h>
#include <hip/hip_fp16.h>

#define N_NODES 50000
#define N_EDGES 800000
#define DIM 64
#define ODIM 32
#define N_GRAPHS 512
#define GEMM_BLOCKS ((N_NODES + 31) / 32) // 1563
#define EPT 5                             // edges per thread (exact: 800000 = 625*256*5)
#define EDGE_BLOCKS (N_EDGES / (256 * EPT))  // 625
#define EDGE_STRIDE (EDGE_BLOCKS * 256)      // 160000

// LDS counting-sort geometry: 125 edge-chunks x 4 node-ranges.
#define NCH 125
#define CHUNK (N_EDGES / NCH)             // 6400
#define SWEEPS (CHUNK / 256)              // 25
#define UNR 5
#define NR 4
#define NRANGE (N_NODES / NR)             // 12500 nodes per range
#define HCOLS (NRANGE / 2)                // 6250 packed-u32 cols (2 nodes/u32)
#define NHB (NCH * NR)                    // 500 hist blocks
#define NCOLS_TOTAL (NR * HCOLS)          // 25000
#define SCAN_NB2 ((N_NODES + 511) / 512)  // 98 (512 nodes per scan block)

__device__ __forceinline__ float bflo(unsigned int u) { return __uint_as_float(u << 16); }
__device__ __forceinline__ float bfhi(unsigned int u) { return __uint_as_float(u & 0xffff0000u); }
__device__ __forceinline__ float h16tof(unsigned int hbits) {
    return __half2float(__ushort_as_half((unsigned short)hbits));
}

// r6/r7/r8 lesson (3 structural failures: spin-RMW 585us, read-poll 724us,
// per-block acq-rel 963us): ANY device-scope sync woven into the hot path
// costs far more than the ~4us/dispatch it saves on this chip. Topology is
// locked to the r5 7-dispatch structure; changes are kernel-internal only.
// This round's A/B: non-temporal hints on streaming accesses (edges, bf2
// store, scatter streams) to preserve L2 for the gather-hot H rows.

// ---- fused: LDS-histogram count (zero global atomics) + layer-1 GEMM ----

__global__ __launch_bounds__(256) void prep_gemm(const int* __restrict__ dst,
                                                 unsigned short* __restrict__ rank,
                                                 unsigned int* __restrict__ cnt_blocks,
                                                 const float* __restrict__ X,
                                                 const float* __restrict__ W,
                                                 __hip_bfloat16* __restrict__ Ybf) {
    __shared__ unsigned int smem[HCOLS];   // 25KB; GEMM reuses as float Ws[4096] (16KB)
    if (blockIdx.x < NHB) {
        unsigned int* hist = smem;
        int c = blockIdx.x >> 2, r = blockIdx.x & 3;
        for (int i = threadIdx.x; i < HCOLS; i += 256) hist[i] = 0;
        __syncthreads();
        int lo = r * NRANGE;
        int base = c * CHUNK + threadIdx.x;
#pragma unroll 1
        for (int b = 0; b < SWEEPS / UNR; ++b) {
            int d[UNR];
#pragma unroll
            for (int u = 0; u < UNR; ++u)                 // 5 loads in flight
                d[u] = dst[base + (b * UNR + u) * 256];
#pragma unroll
            for (int u = 0; u < UNR; ++u) {
                unsigned int ld = (unsigned int)(d[u] - lo);
                if (ld < (unsigned int)NRANGE) {
                    unsigned int sh = (ld & 1u) * 16u;
                    unsigned int ret = atomicAdd(&hist[ld >> 1], 1u << sh);
                    rank[base + (b * UNR + u) * 256] = (unsigned short)((ret >> sh) & 0xffffu);
                }
            }
        }
        __syncthreads();
        unsigned int* out = cnt_blocks + (size_t)blockIdx.x * HCOLS;
        for (int i = threadIdx.x; i < HCOLS; i += 256) out[i] = hist[i];
        return;
    }
    // ---- GEMM part: h = X @ W (N x 64 @ 64 x 64), bf16 out ----
    int bid = blockIdx.x - NHB;
    float* Ws = (float*)smem;
    for (int i = threadIdx.x; i < 64 * 64; i += 256) Ws[i] = W[i];
    __syncthreads();
    int wave = threadIdx.x >> 6;
    int j    = threadIdx.x & 63;
    int row0 = (bid * 4 + wave) * 8;
    if (row0 >= N_NODES) return;
    float acc[8] = {0,0,0,0,0,0,0,0};
    const float* x0 = X + (size_t)row0 * DIM;   // wave-uniform
    int nr = (row0 + 8 <= N_NODES) ? 8 : (N_NODES - row0);
    if (nr == 8) {
#pragma unroll
        for (int k4 = 0; k4 < 16; ++k4) {
            float w0 = Ws[(4 * k4 + 0) * 64 + j];
            float w1 = Ws[(4 * k4 + 1) * 64 + j];
            float w2 = Ws[(4 * k4 + 2) * 64 + j];
            float w3 = Ws[(4 * k4 + 3) * 64 + j];
#pragma unroll
            for (int r = 0; r < 8; ++r) {
                float4 x4 = *(const float4*)&x0[r * DIM + k4 * 4];
                acc[r] = fmaf(x4.x, w0, acc[r]);
                acc[r] = fmaf(x4.y, w1, acc[r]);
                acc[r] = fmaf(x4.z, w2, acc[r]);
                acc[r] = fmaf(x4.w, w3, acc[r]);
            }
        }
    } else {
        for (int k4 = 0; k4 < 16; ++k4) {
            float w0 = Ws[(4 * k4 + 0) * 64 + j];
            float w1 = Ws[(4 * k4 + 1) * 64 + j];
            float w2 = Ws[(4 * k4 + 2) * 64 + j];
            float w3 = Ws[(4 * k4 + 3) * 64 + j];
            for (int r = 0; r < nr; ++r) {
                float4 x4 = *(const float4*)&x0[r * DIM + k4 * 4];
                acc[r] = fmaf(x4.x, w0, acc[r]);
                acc[r] = fmaf(x4.y, w1, acc[r]);
                acc[r] = fmaf(x4.z, w2, acc[r]);
                acc[r] = fmaf(x4.w, w3, acc[r]);
            }
        }
    }
    for (int r = 0; r < nr; ++r)
        Ybf[(size_t)(row0 + r) * DIM + j] = __float2bfloat16(acc[r]);
}

// ---- column scan + fused block-sum reduction + sums zeroing ----

__global__ __launch_bounds__(256) void colscan(const unsigned int* __restrict__ cnt_blocks,
                                               unsigned int* __restrict__ blockbase,
                                               int* __restrict__ deg,
                                               int* __restrict__ blocksum,
                                               float* __restrict__ sums) {
    __shared__ int ws[4];
    int q = blockIdx.x * 256 + threadIdx.x;
    int d0 = 0, d1 = 0;
    if (q < NCOLS_TOTAL) {
        int r = q / HCOLS, col = q % HCOLS;
        unsigned int run = 0;
#pragma unroll 5
        for (int c = 0; c < NCH; ++c) {
            size_t idx = (size_t)(c * NR + r) * HCOLS + col;
            unsigned int v = cnt_blocks[idx];
            blockbase[idx] = run;      // exclusive prefix (packed u16x2)
            run += v;
        }
        d0 = (int)(run & 0xffffu);
        d1 = (int)(run >> 16);
        deg[2 * q]     = d0;
        deg[2 * q + 1] = d1;
    }
    int v = d0 + d1;
    for (int d = 32; d > 0; d >>= 1) v += __shfl_down(v, d, 64);
    int lane = threadIdx.x & 63, wid = threadIdx.x >> 6;
    if (lane == 0) ws[wid] = v;
    __syncthreads();
    if (threadIdx.x == 0) blocksum[blockIdx.x] = ws[0] + ws[1] + ws[2] + ws[3];
    if (blockIdx.x == 0)
        for (int i = threadIdx.x; i < N_GRAPHS * DIM; i += 256) sums[i] = 0.f;
}

// ---- final scan: 512 nodes/block (2/thread) ----

__global__ __launch_bounds__(256) void scan_p3(const int* __restrict__ deg,
                                               const int* __restrict__ blocksum,
                                               int* __restrict__ off,
                                               float* __restrict__ inv_sqrt,
                                               float* __restrict__ invdeg) {
    __shared__ int wtot[4];
    __shared__ int bb[SCAN_NB2 + 1];
    {
        int t = threadIdx.x;
        int v = (t < SCAN_NB2) ? blocksum[t] : 0;
        int lane = t & 63, wid = t >> 6;
        int incl = v;
        for (int d = 1; d < 64; d <<= 1) {
            int u = __shfl_up(incl, d, 64);
            if (lane >= d) incl += u;
        }
        if (lane == 63) wtot[wid] = incl;
        __syncthreads();
        int base = 0;
        for (int w = 0; w < wid; ++w) base += wtot[w];
        incl += base;
        if (t <= SCAN_NB2) bb[t] = incl - v;   // exclusive; bb[SCAN_NB2] = total
        __syncthreads();
    }
    if (blockIdx.x == 0 && threadIdx.x == 0) off[N_NODES] = bb[SCAN_NB2];
    __syncthreads();

    int n = blockIdx.x * 512 + 2 * threadIdx.x;
    int d0 = 0, d1 = 0;
    if (n < N_NODES) { int2 dd = *(const int2*)&deg[n]; d0 = dd.x; d1 = dd.y; }
    int v = d0 + d1;
    int lane = threadIdx.x & 63, wid = threadIdx.x >> 6;
    int incl = v;
    for (int d = 1; d < 64; d <<= 1) {
        int u = __shfl_up(incl, d, 64);
        if (lane >= d) incl += u;
    }
    if (lane == 63) wtot[wid] = incl;
    __syncthreads();
    int base = bb[blockIdx.x];
    for (int w = 0; w < wid; ++w) base += wtot[w];
    int excl = base + incl - v;
    if (n < N_NODES) {
        off[n]     = excl;
        off[n + 1] = excl + d0;
        float f0 = (float)(d0 + 1), f1 = (float)(d1 + 1);   // +1: self-loop
        inv_sqrt[n]     = rsqrtf(f0);
        inv_sqrt[n + 1] = rsqrtf(f1);
        invdeg[n]       = 1.0f / f0;
        invdeg[n + 1]   = 1.0f / f1;
    }
}

// ---- atomic-free scatter: pos = off[d] + blockbase(chunk,d) + rank ----
// Streaming in marked nt (read-once; keep L2 for downstream gathers).

__global__ __launch_bounds__(256) void scatter_edges(const int* __restrict__ src,
                                                     const int* __restrict__ dst,
                                                     const unsigned short* __restrict__ rank,
                                                     const int* __restrict__ off,
                                                     const unsigned int* __restrict__ blockbase,
                                                     const float* __restrict__ inv_sqrt,
                                                     unsigned int* __restrict__ edges) {
    int t = blockIdx.x * 256 + threadIdx.x;
    int d[EPT], s[EPT];
    unsigned short rk[EPT];
#pragma unroll
    for (int i = 0; i < EPT; ++i) d[i] = __builtin_nontemporal_load(&dst[t + i * EDGE_STRIDE]);
#pragma unroll
    for (int i = 0; i < EPT; ++i) s[i] = __builtin_nontemporal_load(&src[t + i * EDGE_STRIDE]);
#pragma unroll
    for (int i = 0; i < EPT; ++i) rk[i] = __builtin_nontemporal_load(&rank[t + i * EDGE_STRIDE]);
    int pos[EPT];
    float w[EPT];
#pragma unroll
    for (int i = 0; i < EPT; ++i) {
        int e = t + i * EDGE_STRIDE;
        int c = e / CHUNK;
        int r = d[i] / NRANGE;
        int ld = d[i] - r * NRANGE;
        unsigned int bb = blockbase[(size_t)(c * NR + r) * HCOLS + (ld >> 1)];
        int base16 = (int)((bb >> ((ld & 1) * 16)) & 0xffffu);
        pos[i] = off[d[i]] + base16 + (int)rk[i];
    }
#pragma unroll
    for (int i = 0; i < EPT; ++i) w[i] = inv_sqrt[s[i]];
#pragma unroll
    for (int i = 0; i < EPT; ++i) {
        unsigned short hw = __half_as_ushort(__float2half(w[i]));
        edges[pos[i]] = (unsigned int)s[i] | ((unsigned int)hw << 16);
    }
}

// ---- half-wave packed merged-stream gather for 4 consecutive nodes ----
// Depth-3 pipeline (r5-identical) + nt edge loads: the 3.2MB edge stream is
// read-once per kernel and must not evict gather-hot H rows from L2.
__device__ __forceinline__ void gather4_packed(
    const unsigned int* __restrict__ H2,
    const unsigned int* __restrict__ edges,
    int e0, int b1, int b2, int b3, int e4, int m, int h,
    float (&aLo)[4], float (&aHi)[4])
{
    int k = e0;
    int B = (e4 - e0) >> 3;

    unsigned int E0[4], E1[4], E2[4];
    unsigned int U0[4], U1[4];

    auto ld4 = [&](unsigned int* E, int kb) {
#pragma unroll
        for (int i = 0; i < 4; ++i) E[i] = __builtin_nontemporal_load(&edges[kb + 2 * i + h]);
    };
    auto gt4 = [&](unsigned int* U, const unsigned int* E) {
#pragma unroll
        for (int i = 0; i < 4; ++i)
            U[i] = H2[(size_t)(E[i] & 0xffffu) * 32 + m];
    };
    auto consume = [&](const unsigned int* E, const unsigned int* U, int kb) {
        int selA = (kb >= b1) + (kb >= b2) + (kb >= b3);
        int selB = (kb + 7 >= b1) + (kb + 7 >= b2) + (kb + 7 >= b3);
        if (selA == selB) {                 // whole batch in one node (common)
            float sLo = 0.f, sHi = 0.f;
#pragma unroll
            for (int i = 0; i < 4; ++i) {
                float w = h16tof(E[i] >> 16);
                sLo = fmaf(bflo(U[i]), w, sLo);
                sHi = fmaf(bfhi(U[i]), w, sHi);
            }
            if      (selA == 0) { aLo[0] += sLo; aHi[0] += sHi; }
            else if (selA == 1) { aLo[1] += sLo; aHi[1] += sHi; }
            else if (selA == 2) { aLo[2] += sLo; aHi[2] += sHi; }
            else                { aLo[3] += sLo; aHi[3] += sHi; }
        } else {                            // boundary batch: per-edge select
#pragma unroll
            for (int i = 0; i < 4; ++i) {
                int kk = kb + 2 * i + h;
                float w = h16tof(E[i] >> 16);
                float pLo = bflo(U[i]) * w;
                float pHi = bfhi(U[i]) * w;
                int sel = (kk >= b1) + (kk >= b2) + (kk >= b3);
                aLo[0] += (sel == 0) ? pLo : 0.f;  aHi[0] += (sel == 0) ? pHi : 0.f;
                aLo[1] += (sel == 1) ? pLo : 0.f;  aHi[1] += (sel == 1) ? pHi : 0.f;
                aLo[2] += (sel == 2) ? pLo : 0.f;  aHi[2] += (sel == 2) ? pHi : 0.f;
                aLo[3] += (sel == 3) ? pLo : 0.f;  aHi[3] += (sel == 3) ? pHi : 0.f;
            }
        }
    };

    if (B >= 3) {
        ld4(E0, k);      gt4(U0, E0);
        ld4(E1, k + 8);  gt4(U1, E1);
        ld4(E2, k + 16);
        for (int b = 0; b < B - 3; ++b) {
            unsigned int U2[4];
            gt4(U2, E2);              // batch b+2 gathers in flight
            unsigned int E3[4];
            ld4(E3, k + 24);          // batch b+3 edge loads in flight
            consume(E0, U0, k);       // waits only on batch b gathers
#pragma unroll
            for (int i = 0; i < 4; ++i) {
                E0[i] = E1[i]; U0[i] = U1[i];
                E1[i] = E2[i]; U1[i] = U2[i];
                E2[i] = E3[i];
            }
            k += 8;
        }
        {
            unsigned int U2[4];
            gt4(U2, E2);
            consume(E0, U0, k); k += 8;
            consume(E1, U1, k); k += 8;
            consume(E2, U2, k); k += 8;
        }
    } else if (B == 2) {
        ld4(E0, k);     gt4(U0, E0);
        ld4(E1, k + 8); gt4(U1, E1);
        consume(E0, U0, k); k += 8;
        consume(E1, U1, k); k += 8;
    } else if (B == 1) {
        ld4(E0, k); gt4(U0, E0); consume(E0, U0, k); k += 8;
    }
    for (; k < e4; ++k) {
        if ((k & 1) == h) {       // split tail edges between halves
            unsigned int e = __builtin_nontemporal_load(&edges[k]);
            unsigned int u = H2[(size_t)(e & 0xffffu) * 32 + m];
            float w = h16tof(e >> 16);
            float pLo = bflo(u) * w;
            float pHi = bfhi(u) * w;
            int sel = (k >= b1) + (k >= b2) + (k >= b3);
            aLo[0] += (sel == 0) ? pLo : 0.f;  aHi[0] += (sel == 0) ? pHi : 0.f;
            aLo[1] += (sel == 1) ? pLo : 0.f;  aHi[1] += (sel == 1) ? pHi : 0.f;
            aLo[2] += (sel == 2) ? pLo : 0.f;  aHi[2] += (sel == 2) ? pHi : 0.f;
            aLo[3] += (sel == 3) ? pLo : 0.f;  aHi[3] += (sel == 3) ? pHi : 0.f;
        }
    }
}

// ---- fused: layer-1 aggregate (+bias1, relu) THEN layer-2 gemm (@W2) ----
// nt store for bf2: the reader sits on another XCD 7/8 of the time (per-XCD
// L2 not shared), so push it toward L3 and keep this XCD's L2 for gathers.

__global__ __launch_bounds__(256) void agg_gemm(const __hip_bfloat16* __restrict__ Hbf,
                                                const int* __restrict__ off,
                                                const unsigned int* __restrict__ edges,
                                                const float* __restrict__ inv_sqrt,
                                                const float* __restrict__ invdeg,
                                                const float* __restrict__ bias,
                                                const float* __restrict__ W2,
                                                __hip_bfloat16* __restrict__ Ybf2) {
    __shared__ float Ws[64 * 64];
    __shared__ float rowbuf[4][4][64];   // [wave][r][j]
    for (int i = threadIdx.x; i < 64 * 64; i += 256) Ws[i] = W2[i];
    __syncthreads();
    const unsigned int* H2 = (const unsigned int*)Hbf;
    int wave = threadIdx.x >> 6;
    int j    = threadIdx.x & 63;
    int m = j & 31, h = j >> 5;
    int n0   = (blockIdx.x * 4 + wave) * 4;   // N_NODES = 16*3125: exact
    int e0 = off[n0], b1v = off[n0 + 1], b2v = off[n0 + 2], b3v = off[n0 + 3], e4 = off[n0 + 4];
    float aLo[4] = {0.f, 0.f, 0.f, 0.f};
    float aHi[4] = {0.f, 0.f, 0.f, 0.f};
    gather4_packed(H2, edges, e0, b1v, b2v, b3v, e4, m, h, aLo, aHi);
    float bLo = bias[2 * m], bHi = bias[2 * m + 1];
#pragma unroll
    for (int r = 0; r < 4; ++r) {
        aLo[r] += __shfl_xor(aLo[r], 32);
        aHi[r] += __shfl_xor(aHi[r], 32);
        float isq = inv_sqrt[n0 + r];
        aLo[r] *= isq;
        aHi[r] *= isq;
        unsigned int u = H2[(size_t)(n0 + r) * 32 + m];   // self row
        float iv = invdeg[n0 + r];
        float vLo = fmaf(bflo(u), iv, aLo[r]) + bLo;
        float vHi = fmaf(bfhi(u), iv, aHi[r]) + bHi;
        if (h == 0) {
            rowbuf[wave][r][2 * m]     = fmaxf(vLo, 0.f);
            rowbuf[wave][r][2 * m + 1] = fmaxf(vHi, 0.f);
        }
    }
    // same-wave LDS write->read: compiler inserts lgkmcnt wait; no barrier needed
    float acc2[4] = {0.f, 0.f, 0.f, 0.f};
#pragma unroll
    for (int k4 = 0; k4 < 16; ++k4) {
        float w0 = Ws[(4 * k4 + 0) * 64 + j];
        float w1 = Ws[(4 * k4 + 1) * 64 + j];
        float w2 = Ws[(4 * k4 + 2) * 64 + j];
        float w3 = Ws[(4 * k4 + 3) * 64 + j];
#pragma unroll
        for (int r = 0; r < 4; ++r) {
            float4 h4 = *(const float4*)&rowbuf[wave][r][k4 * 4];  // broadcast: free
            acc2[r] = fmaf(h4.x, w0, acc2[r]);
            acc2[r] = fmaf(h4.y, w1, acc2[r]);
            acc2[r] = fmaf(h4.z, w2, acc2[r]);
            acc2[r] = fmaf(h4.w, w3, acc2[r]);
        }
    }
#pragma unroll
    for (int r = 0; r < 4; ++r) {
        unsigned short b = __hip_bfloat16_raw(__float2bfloat16(acc2[r])).x;
        __builtin_nontemporal_store(b, (unsigned short*)&Ybf2[(size_t)(n0 + r) * DIM + j]);
    }
}

// ---- layer-2 aggregate (+bias2, relu) fused with mean-pool accumulation ----

__global__ __launch_bounds__(256) void agg_pool(const __hip_bfloat16* __restrict__ Hbf,
                                                const int* __restrict__ off,
                                                const unsigned int* __restrict__ edges,
                                                const float* __restrict__ inv_sqrt,
                                                const float* __restrict__ invdeg,
                                                const float* __restrict__ bias,
                                                const int* __restrict__ batch,
                                                float* __restrict__ sums) {
    const unsigned int* H2 = (const unsigned int*)Hbf;
    int wave = threadIdx.x >> 6;
    int j    = threadIdx.x & 63;
    int m = j & 31, h = j >> 5;
    int n0   = (blockIdx.x * 4 + wave) * 4;   // exact
    int e0 = off[n0], b1v = off[n0 + 1], b2v = off[n0 + 2], b3v = off[n0 + 3], e4 = off[n0 + 4];
    float aLo[4] = {0.f, 0.f, 0.f, 0.f};
    float aHi[4] = {0.f, 0.f, 0.f, 0.f};
    gather4_packed(H2, edges, e0, b1v, b2v, b3v, e4, m, h, aLo, aHi);
    float bLo = bias[2 * m], bHi = bias[2 * m + 1];
    float vLo[4], vHi[4];
#pragma unroll
    for (int r = 0; r < 4; ++r) {
        aLo[r] += __shfl_xor(aLo[r], 32);
        aHi[r] += __shfl_xor(aHi[r], 32);
        float isq = inv_sqrt[n0 + r];
        aLo[r] *= isq;
        aHi[r] *= isq;
        unsigned int u = H2[(size_t)(n0 + r) * 32 + m];
        float iv = invdeg[n0 + r];
        vLo[r] = fmaxf(fmaf(bflo(u), iv, aLo[r]) + bLo, 0.f);
        vHi[r] = fmaxf(fmaf(bfhi(u), iv, aHi[r]) + bHi, 0.f);
    }
    if (h == 0) {
        int g0 = batch[n0], g3 = batch[n0 + 3];
        if (g0 == g3) {
            atomicAdd(&sums[g0 * DIM + 2 * m],     (vLo[0] + vLo[1]) + (vLo[2] + vLo[3]));
            atomicAdd(&sums[g0 * DIM + 2 * m + 1], (vHi[0] + vHi[1]) + (vHi[2] + vHi[3]));
        } else {
#pragma unroll
            for (int r = 0; r < 4; ++r) {
                int g = batch[n0 + r];
                atomicAdd(&sums[g * DIM + 2 * m],     vLo[r]);
                atomicAdd(&sums[g * DIM + 2 * m + 1], vHi[r]);
            }
        }
    }
}

// ---- FC over pooled means: one 64-thread block per graph ----

__global__ __launch_bounds__(64) void fc(const float* __restrict__ sums,
                                         const int* __restrict__ batch,
                                         const float* __restrict__ fcW,
                                         const float* __restrict__ fcb,
                                         float* __restrict__ out) {
    __shared__ float mean[64];
    int g = blockIdx.x;
    int lo = 0, hi = N_NODES;
    while (lo < hi) { int mid = (lo + hi) >> 1; if (batch[mid] < g) lo = mid + 1; else hi = mid; }
    int start = lo;
    hi = N_NODES;
    while (lo < hi) { int mid = (lo + hi) >> 1; if (batch[mid] < g + 1) lo = mid + 1; else hi = mid; }
    int end = lo;
    float inv = 1.0f / fmaxf((float)(end - start), 1.0f);
    mean[threadIdx.x] = sums[g * DIM + threadIdx.x] * inv;   // same-wave LDS, no barrier
    if (threadIdx.x < ODIM) {
        int jj = threadIdx.x;
        float a = fcb[jj];
#pragma unroll
        for (int k = 0; k < DIM; ++k) a = fmaf(mean[k], fcW[k * ODIM + jj], a);
        out[g * ODIM + jj] = a;
    }
}

extern "C" void kernel_launch(void* const* d_in, const int* in_sizes, int n_in,
                              void* d_out, int out_size, void* d_ws, size_t ws_size,
                              hipStream_t stream) {
    const float* x    = (const float*)d_in[0];
    const float* W1   = (const float*)d_in[1];
    const float* b1   = (const float*)d_in[2];
    const float* W2   = (const float*)d_in[3];
    const float* b2   = (const float*)d_in[4];
    const float* fcW  = (const float*)d_in[5];
    const float* fcb  = (const float*)d_in[6];
    const int*   eidx = (const int*)d_in[7];
    const int*   batch= (const int*)d_in[8];
    const int* esrc = eidx;
    const int* edst = eidx + N_EDGES;
    float* out = (float*)d_out;

    char* ws = (char*)d_ws;
    size_t o = 0;
    auto alloc = [&](size_t bytes) {
        void* p = ws + o;
        o += (bytes + 255) & ~(size_t)255;
        return p;
    };
    float* sums     = (float*)alloc((size_t)N_GRAPHS * DIM * 4);   // zeroed by colscan block 0
    __hip_bfloat16* bf1 = (__hip_bfloat16*)alloc((size_t)N_NODES * DIM * 2);
    __hip_bfloat16* bf2 = (__hip_bfloat16*)alloc((size_t)N_NODES * DIM * 2);
    int*   deg      = (int*)  alloc((size_t)N_NODES * 4);
    int*   off      = (int*)  alloc((size_t)(N_NODES + 1) * 4);
    float* inv_sqrt = (float*)alloc((size_t)N_NODES * 4);
    float* invdeg   = (float*)alloc((size_t)N_NODES * 4);
    unsigned short* rank = (unsigned short*)alloc((size_t)N_EDGES * 2);
    unsigned int* edges = (unsigned int*)alloc((size_t)N_EDGES * 4);
    unsigned int* cnt_blocks = (unsigned int*)alloc((size_t)NHB * HCOLS * 4);  // 12.5MB
    unsigned int* blockbase  = (unsigned int*)alloc((size_t)NHB * HCOLS * 4);  // 12.5MB
    int*   blocksum = (int*)  alloc((size_t)SCAN_NB2 * 4);

    prep_gemm<<<NHB + GEMM_BLOCKS, 256, 0, stream>>>(edst, rank, cnt_blocks, x, W1, bf1);
    colscan<<<SCAN_NB2, 256, 0, stream>>>(cnt_blocks, blockbase, deg, blocksum, sums);
    scan_p3<<<SCAN_NB2, 256, 0, stream>>>(deg, blocksum, off, inv_sqrt, invdeg);
    scatter_edges<<<EDGE_BLOCKS, 256, 0, stream>>>(esrc, edst, rank, off, blockbase, inv_sqrt, edges);

    agg_gemm<<<N_NODES / 16, 256, 0, stream>>>(bf1, off, edges, inv_sqrt, invdeg, b1, W2, bf2);
    agg_pool<<<N_NODES / 16, 256, 0, stream>>>(bf2, off, edges, inv_sqrt, invdeg, b2, batch, sums);

    fc<<<N_GRAPHS, 64, 0, stream>>>(sums, batch, fcW, fcb, out);
}

// Round 10
// 221.591 us; speedup vs baseline: 4.3467x; 1.0083x over previous
//
#include <hip/hip_runtime.h>
#include <hip/hip_bf16.h>
#include <hip/hip_fp16.h>

#define N_NODES 50000
#define N_EDGES 800000
#define DIM 64
#define ODIM 32
#define N_GRAPHS 512
#define GEMM_BLOCKS ((N_NODES + 31) / 32) // 1563
#define EPT 5                             // edges per thread (exact: 800000 = 625*256*5)
#define EDGE_BLOCKS (N_EDGES / (256 * EPT))  // 625
#define EDGE_STRIDE (EDGE_BLOCKS * 256)      // 160000

// LDS counting-sort geometry: 125 edge-chunks x 4 node-ranges.
#define NCH 125
#define CHUNK (N_EDGES / NCH)             // 6400
#define SWEEPS (CHUNK / 256)              // 25
#define UNR 5
#define NR 4
#define NRANGE (N_NODES / NR)             // 12500 nodes per range
#define HCOLS (NRANGE / 2)                // 6250 packed-u32 cols (2 nodes/u32)
#define NHB (NCH * NR)                    // 500 hist blocks
#define NCOLS_TOTAL (NR * HCOLS)          // 25000
#define SCAN_NB2 ((N_NODES + 511) / 512)  // 98 (512 nodes per scan block)

#define AGG_TILES (N_NODES / 16)          // 3125
#define POOL_BLOCKS (782 * 8)             // 6256: each tile once per feature-half

__device__ __forceinline__ float bflo(unsigned int u) { return __uint_as_float(u << 16); }
__device__ __forceinline__ float bfhi(unsigned int u) { return __uint_as_float(u & 0xffff0000u); }
__device__ __forceinline__ float h16tof(unsigned int hbits) {
    return __half2float(__ushort_as_half((unsigned short)hbits));
}

// Topology locked to r5 7-dispatch structure (r6/r7/r8: all device-sync-in-
// hot-path variants regressed 2.7-4.5x). r9: nt hints on edges/stores cost
// +10us (edges ARE part of the L2 hot set) -> reverted. This round's single
// A/B: feature-split agg_pool by XCD (per-XCD gather hot set 6.4 -> 3.2MB
// < 4MB L2). agg_gemm untouched (layer-2 GEMM needs full rows).

// ---- fused: LDS-histogram count (zero global atomics) + layer-1 GEMM ----

__global__ __launch_bounds__(256) void prep_gemm(const int* __restrict__ dst,
                                                 unsigned short* __restrict__ rank,
                                                 unsigned int* __restrict__ cnt_blocks,
                                                 const float* __restrict__ X,
                                                 const float* __restrict__ W,
                                                 __hip_bfloat16* __restrict__ Ybf) {
    __shared__ unsigned int smem[HCOLS];   // 25KB; GEMM reuses as float Ws[4096] (16KB)
    if (blockIdx.x < NHB) {
        unsigned int* hist = smem;
        int c = blockIdx.x >> 2, r = blockIdx.x & 3;
        for (int i = threadIdx.x; i < HCOLS; i += 256) hist[i] = 0;
        __syncthreads();
        int lo = r * NRANGE;
        int base = c * CHUNK + threadIdx.x;
#pragma unroll 1
        for (int b = 0; b < SWEEPS / UNR; ++b) {
            int d[UNR];
#pragma unroll
            for (int u = 0; u < UNR; ++u)                 // 5 loads in flight
                d[u] = dst[base + (b * UNR + u) * 256];
#pragma unroll
            for (int u = 0; u < UNR; ++u) {
                unsigned int ld = (unsigned int)(d[u] - lo);
                if (ld < (unsigned int)NRANGE) {
                    unsigned int sh = (ld & 1u) * 16u;
                    unsigned int ret = atomicAdd(&hist[ld >> 1], 1u << sh);
                    rank[base + (b * UNR + u) * 256] = (unsigned short)((ret >> sh) & 0xffffu);
                }
            }
        }
        __syncthreads();
        unsigned int* out = cnt_blocks + (size_t)blockIdx.x * HCOLS;
        for (int i = threadIdx.x; i < HCOLS; i += 256) out[i] = hist[i];
        return;
    }
    // ---- GEMM part: h = X @ W (N x 64 @ 64 x 64), bf16 out ----
    int bid = blockIdx.x - NHB;
    float* Ws = (float*)smem;
    for (int i = threadIdx.x; i < 64 * 64; i += 256) Ws[i] = W[i];
    __syncthreads();
    int wave = threadIdx.x >> 6;
    int j    = threadIdx.x & 63;
    int row0 = (bid * 4 + wave) * 8;
    if (row0 >= N_NODES) return;
    float acc[8] = {0,0,0,0,0,0,0,0};
    const float* x0 = X + (size_t)row0 * DIM;   // wave-uniform
    int nr = (row0 + 8 <= N_NODES) ? 8 : (N_NODES - row0);
    if (nr == 8) {
#pragma unroll
        for (int k4 = 0; k4 < 16; ++k4) {
            float w0 = Ws[(4 * k4 + 0) * 64 + j];
            float w1 = Ws[(4 * k4 + 1) * 64 + j];
            float w2 = Ws[(4 * k4 + 2) * 64 + j];
            float w3 = Ws[(4 * k4 + 3) * 64 + j];
#pragma unroll
            for (int r = 0; r < 8; ++r) {
                float4 x4 = *(const float4*)&x0[r * DIM + k4 * 4];
                acc[r] = fmaf(x4.x, w0, acc[r]);
                acc[r] = fmaf(x4.y, w1, acc[r]);
                acc[r] = fmaf(x4.z, w2, acc[r]);
                acc[r] = fmaf(x4.w, w3, acc[r]);
            }
        }
    } else {
        for (int k4 = 0; k4 < 16; ++k4) {
            float w0 = Ws[(4 * k4 + 0) * 64 + j];
            float w1 = Ws[(4 * k4 + 1) * 64 + j];
            float w2 = Ws[(4 * k4 + 2) * 64 + j];
            float w3 = Ws[(4 * k4 + 3) * 64 + j];
            for (int r = 0; r < nr; ++r) {
                float4 x4 = *(const float4*)&x0[r * DIM + k4 * 4];
                acc[r] = fmaf(x4.x, w0, acc[r]);
                acc[r] = fmaf(x4.y, w1, acc[r]);
                acc[r] = fmaf(x4.z, w2, acc[r]);
                acc[r] = fmaf(x4.w, w3, acc[r]);
            }
        }
    }
    for (int r = 0; r < nr; ++r)
        Ybf[(size_t)(row0 + r) * DIM + j] = __float2bfloat16(acc[r]);
}

// ---- column scan + fused block-sum reduction + sums zeroing ----

__global__ __launch_bounds__(256) void colscan(const unsigned int* __restrict__ cnt_blocks,
                                               unsigned int* __restrict__ blockbase,
                                               int* __restrict__ deg,
                                               int* __restrict__ blocksum,
                                               float* __restrict__ sums) {
    __shared__ int ws[4];
    int q = blockIdx.x * 256 + threadIdx.x;
    int d0 = 0, d1 = 0;
    if (q < NCOLS_TOTAL) {
        int r = q / HCOLS, col = q % HCOLS;
        unsigned int run = 0;
#pragma unroll 5
        for (int c = 0; c < NCH; ++c) {
            size_t idx = (size_t)(c * NR + r) * HCOLS + col;
            unsigned int v = cnt_blocks[idx];
            blockbase[idx] = run;      // exclusive prefix (packed u16x2)
            run += v;
        }
        d0 = (int)(run & 0xffffu);
        d1 = (int)(run >> 16);
        deg[2 * q]     = d0;
        deg[2 * q + 1] = d1;
    }
    int v = d0 + d1;
    for (int d = 32; d > 0; d >>= 1) v += __shfl_down(v, d, 64);
    int lane = threadIdx.x & 63, wid = threadIdx.x >> 6;
    if (lane == 0) ws[wid] = v;
    __syncthreads();
    if (threadIdx.x == 0) blocksum[blockIdx.x] = ws[0] + ws[1] + ws[2] + ws[3];
    if (blockIdx.x == 0)
        for (int i = threadIdx.x; i < N_GRAPHS * DIM; i += 256) sums[i] = 0.f;
}

// ---- final scan: 512 nodes/block (2/thread) ----

__global__ __launch_bounds__(256) void scan_p3(const int* __restrict__ deg,
                                               const int* __restrict__ blocksum,
                                               int* __restrict__ off,
                                               float* __restrict__ inv_sqrt,
                                               float* __restrict__ invdeg) {
    __shared__ int wtot[4];
    __shared__ int bb[SCAN_NB2 + 1];
    {
        int t = threadIdx.x;
        int v = (t < SCAN_NB2) ? blocksum[t] : 0;
        int lane = t & 63, wid = t >> 6;
        int incl = v;
        for (int d = 1; d < 64; d <<= 1) {
            int u = __shfl_up(incl, d, 64);
            if (lane >= d) incl += u;
        }
        if (lane == 63) wtot[wid] = incl;
        __syncthreads();
        int base = 0;
        for (int w = 0; w < wid; ++w) base += wtot[w];
        incl += base;
        if (t <= SCAN_NB2) bb[t] = incl - v;   // exclusive; bb[SCAN_NB2] = total
        __syncthreads();
    }
    if (blockIdx.x == 0 && threadIdx.x == 0) off[N_NODES] = bb[SCAN_NB2];
    __syncthreads();

    int n = blockIdx.x * 512 + 2 * threadIdx.x;
    int d0 = 0, d1 = 0;
    if (n < N_NODES) { int2 dd = *(const int2*)&deg[n]; d0 = dd.x; d1 = dd.y; }
    int v = d0 + d1;
    int lane = threadIdx.x & 63, wid = threadIdx.x >> 6;
    int incl = v;
    for (int d = 1; d < 64; d <<= 1) {
        int u = __shfl_up(incl, d, 64);
        if (lane >= d) incl += u;
    }
    if (lane == 63) wtot[wid] = incl;
    __syncthreads();
    int base = bb[blockIdx.x];
    for (int w = 0; w < wid; ++w) base += wtot[w];
    int excl = base + incl - v;
    if (n < N_NODES) {
        off[n]     = excl;
        off[n + 1] = excl + d0;
        float f0 = (float)(d0 + 1), f1 = (float)(d1 + 1);   // +1: self-loop
        inv_sqrt[n]     = rsqrtf(f0);
        inv_sqrt[n + 1] = rsqrtf(f1);
        invdeg[n]       = 1.0f / f0;
        invdeg[n + 1]   = 1.0f / f1;
    }
}

// ---- atomic-free scatter: pos = off[d] + blockbase(chunk,d) + rank ----

__global__ __launch_bounds__(256) void scatter_edges(const int* __restrict__ src,
                                                     const int* __restrict__ dst,
                                                     const unsigned short* __restrict__ rank,
                                                     const int* __restrict__ off,
                                                     const unsigned int* __restrict__ blockbase,
                                                     const float* __restrict__ inv_sqrt,
                                                     unsigned int* __restrict__ edges) {
    int t = blockIdx.x * 256 + threadIdx.x;
    int d[EPT], s[EPT];
    unsigned short rk[EPT];
#pragma unroll
    for (int i = 0; i < EPT; ++i) d[i] = dst[t + i * EDGE_STRIDE];
#pragma unroll
    for (int i = 0; i < EPT; ++i) s[i] = src[t + i * EDGE_STRIDE];
#pragma unroll
    for (int i = 0; i < EPT; ++i) rk[i] = rank[t + i * EDGE_STRIDE];
    int pos[EPT];
    float w[EPT];
#pragma unroll
    for (int i = 0; i < EPT; ++i) {
        int e = t + i * EDGE_STRIDE;
        int c = e / CHUNK;
        int r = d[i] / NRANGE;
        int ld = d[i] - r * NRANGE;
        unsigned int bb = blockbase[(size_t)(c * NR + r) * HCOLS + (ld >> 1)];
        int base16 = (int)((bb >> ((ld & 1) * 16)) & 0xffffu);
        pos[i] = off[d[i]] + base16 + (int)rk[i];
    }
#pragma unroll
    for (int i = 0; i < EPT; ++i) w[i] = inv_sqrt[s[i]];
#pragma unroll
    for (int i = 0; i < EPT; ++i) {
        unsigned short hw = __half_as_ushort(__float2half(w[i]));
        edges[pos[i]] = (unsigned int)s[i] | ((unsigned int)hw << 16);
    }
}

// ---- half-wave packed merged-stream gather for 4 consecutive nodes ----
// Depth-3 pipeline (r5-identical, no nt). Used by agg_gemm (full rows).
__device__ __forceinline__ void gather4_packed(
    const unsigned int* __restrict__ H2,
    const unsigned int* __restrict__ edges,
    int e0, int b1, int b2, int b3, int e4, int m, int h,
    float (&aLo)[4], float (&aHi)[4])
{
    int k = e0;
    int B = (e4 - e0) >> 3;

    unsigned int E0[4], E1[4], E2[4];
    unsigned int U0[4], U1[4];

    auto ld4 = [&](unsigned int* E, int kb) {
#pragma unroll
        for (int i = 0; i < 4; ++i) E[i] = edges[kb + 2 * i + h];
    };
    auto gt4 = [&](unsigned int* U, const unsigned int* E) {
#pragma unroll
        for (int i = 0; i < 4; ++i)
            U[i] = H2[(size_t)(E[i] & 0xffffu) * 32 + m];
    };
    auto consume = [&](const unsigned int* E, const unsigned int* U, int kb) {
        int selA = (kb >= b1) + (kb >= b2) + (kb >= b3);
        int selB = (kb + 7 >= b1) + (kb + 7 >= b2) + (kb + 7 >= b3);
        if (selA == selB) {                 // whole batch in one node (common)
            float sLo = 0.f, sHi = 0.f;
#pragma unroll
            for (int i = 0; i < 4; ++i) {
                float w = h16tof(E[i] >> 16);
                sLo = fmaf(bflo(U[i]), w, sLo);
                sHi = fmaf(bfhi(U[i]), w, sHi);
            }
            if      (selA == 0) { aLo[0] += sLo; aHi[0] += sHi; }
            else if (selA == 1) { aLo[1] += sLo; aHi[1] += sHi; }
            else if (selA == 2) { aLo[2] += sLo; aHi[2] += sHi; }
            else                { aLo[3] += sLo; aHi[3] += sHi; }
        } else {                            // boundary batch: per-edge select
#pragma unroll
            for (int i = 0; i < 4; ++i) {
                int kk = kb + 2 * i + h;
                float w = h16tof(E[i] >> 16);
                float pLo = bflo(U[i]) * w;
                float pHi = bfhi(U[i]) * w;
                int sel = (kk >= b1) + (kk >= b2) + (kk >= b3);
                aLo[0] += (sel == 0) ? pLo : 0.f;  aHi[0] += (sel == 0) ? pHi : 0.f;
                aLo[1] += (sel == 1) ? pLo : 0.f;  aHi[1] += (sel == 1) ? pHi : 0.f;
                aLo[2] += (sel == 2) ? pLo : 0.f;  aHi[2] += (sel == 2) ? pHi : 0.f;
                aLo[3] += (sel == 3) ? pLo : 0.f;  aHi[3] += (sel == 3) ? pHi : 0.f;
            }
        }
    };

    if (B >= 3) {
        ld4(E0, k);      gt4(U0, E0);
        ld4(E1, k + 8);  gt4(U1, E1);
        ld4(E2, k + 16);
        for (int b = 0; b < B - 3; ++b) {
            unsigned int U2[4];
            gt4(U2, E2);              // batch b+2 gathers in flight
            unsigned int E3[4];
            ld4(E3, k + 24);          // batch b+3 edge loads in flight
            consume(E0, U0, k);       // waits only on batch b gathers
#pragma unroll
            for (int i = 0; i < 4; ++i) {
                E0[i] = E1[i]; U0[i] = U1[i];
                E1[i] = E2[i]; U1[i] = U2[i];
                E2[i] = E3[i];
            }
            k += 8;
        }
        {
            unsigned int U2[4];
            gt4(U2, E2);
            consume(E0, U0, k); k += 8;
            consume(E1, U1, k); k += 8;
            consume(E2, U2, k); k += 8;
        }
    } else if (B == 2) {
        ld4(E0, k);     gt4(U0, E0);
        ld4(E1, k + 8); gt4(U1, E1);
        consume(E0, U0, k); k += 8;
        consume(E1, U1, k); k += 8;
    } else if (B == 1) {
        ld4(E0, k); gt4(U0, E0); consume(E0, U0, k); k += 8;
    }
    for (; k < e4; ++k) {
        if ((k & 1) == h) {       // split tail edges between halves
            unsigned int e = edges[k];
            unsigned int u = H2[(size_t)(e & 0xffffu) * 32 + m];
            float w = h16tof(e >> 16);
            float pLo = bflo(u) * w;
            float pHi = bfhi(u) * w;
            int sel = (k >= b1) + (k >= b2) + (k >= b3);
            aLo[0] += (sel == 0) ? pLo : 0.f;  aHi[0] += (sel == 0) ? pHi : 0.f;
            aLo[1] += (sel == 1) ? pLo : 0.f;  aHi[1] += (sel == 1) ? pHi : 0.f;
            aLo[2] += (sel == 2) ? pLo : 0.f;  aHi[2] += (sel == 2) ? pHi : 0.f;
            aLo[3] += (sel == 3) ? pLo : 0.f;  aHi[3] += (sel == 3) ? pHi : 0.f;
        }
    }
}

// ---- quarter-wave gather for the feature-split pool ----
// Lanes: m=j&15 (16 uints = half row), h=j>>4 in [0,4): one gather instr
// serves 4 edges. mm = fh*16+m confines all gathers to one 3.2MB half.
__device__ __forceinline__ void gatherQ(
    const unsigned int* __restrict__ H2,
    const unsigned int* __restrict__ edges,
    int e0, int b1, int b2, int b3, int e4, int mm, int h,
    float (&aLo)[4], float (&aHi)[4])
{
    int k = e0;
    int B = (e4 - e0) >> 3;   // batches of 8 edges (2 per h-group)

    unsigned int E0[2], E1[2], E2[2];
    unsigned int U0[2], U1[2];

    auto ld2 = [&](unsigned int* E, int kb) {
#pragma unroll
        for (int i = 0; i < 2; ++i) E[i] = edges[kb + 4 * i + h];
    };
    auto gt2 = [&](unsigned int* U, const unsigned int* E) {
#pragma unroll
        for (int i = 0; i < 2; ++i)
            U[i] = H2[(size_t)(E[i] & 0xffffu) * 32 + mm];
    };
    auto consume = [&](const unsigned int* E, const unsigned int* U, int kb) {
        int selA = (kb >= b1) + (kb >= b2) + (kb >= b3);
        int selB = (kb + 7 >= b1) + (kb + 7 >= b2) + (kb + 7 >= b3);
        if (selA == selB) {                 // whole batch in one node (common)
            float sLo = 0.f, sHi = 0.f;
#pragma unroll
            for (int i = 0; i < 2; ++i) {
                float w = h16tof(E[i] >> 16);
                sLo = fmaf(bflo(U[i]), w, sLo);
                sHi = fmaf(bfhi(U[i]), w, sHi);
            }
            if      (selA == 0) { aLo[0] += sLo; aHi[0] += sHi; }
            else if (selA == 1) { aLo[1] += sLo; aHi[1] += sHi; }
            else if (selA == 2) { aLo[2] += sLo; aHi[2] += sHi; }
            else                { aLo[3] += sLo; aHi[3] += sHi; }
        } else {                            // boundary batch: per-edge select
#pragma unroll
            for (int i = 0; i < 2; ++i) {
                int kk = kb + 4 * i + h;
                float w = h16tof(E[i] >> 16);
                float pLo = bflo(U[i]) * w;
                float pHi = bfhi(U[i]) * w;
                int sel = (kk >= b1) + (kk >= b2) + (kk >= b3);
                aLo[0] += (sel == 0) ? pLo : 0.f;  aHi[0] += (sel == 0) ? pHi : 0.f;
                aLo[1] += (sel == 1) ? pLo : 0.f;  aHi[1] += (sel == 1) ? pHi : 0.f;
                aLo[2] += (sel == 2) ? pLo : 0.f;  aHi[2] += (sel == 2) ? pHi : 0.f;
                aLo[3] += (sel == 3) ? pLo : 0.f;  aHi[3] += (sel == 3) ? pHi : 0.f;
            }
        }
    };

    if (B >= 3) {
        ld2(E0, k);      gt2(U0, E0);
        ld2(E1, k + 8);  gt2(U1, E1);
        ld2(E2, k + 16);
        for (int b = 0; b < B - 3; ++b) {
            unsigned int U2[2];
            gt2(U2, E2);              // batch b+2 gathers in flight
            unsigned int E3[2];
            ld2(E3, k + 24);          // batch b+3 edge loads in flight
            consume(E0, U0, k);       // waits only on batch b gathers
#pragma unroll
            for (int i = 0; i < 2; ++i) {
                E0[i] = E1[i]; U0[i] = U1[i];
                E1[i] = E2[i]; U1[i] = U2[i];
                E2[i] = E3[i];
            }
            k += 8;
        }
        {
            unsigned int U2[2];
            gt2(U2, E2);
            consume(E0, U0, k); k += 8;
            consume(E1, U1, k); k += 8;
            consume(E2, U2, k); k += 8;
        }
    } else if (B == 2) {
        ld2(E0, k);     gt2(U0, E0);
        ld2(E1, k + 8); gt2(U1, E1);
        consume(E0, U0, k); k += 8;
        consume(E1, U1, k); k += 8;
    } else if (B == 1) {
        ld2(E0, k); gt2(U0, E0); consume(E0, U0, k); k += 8;
    }
    for (; k < e4; ++k) {
        if ((k & 3) == h) {       // split tail edges across the 4 h-groups
            unsigned int e = edges[k];
            unsigned int u = H2[(size_t)(e & 0xffffu) * 32 + mm];
            float w = h16tof(e >> 16);
            float pLo = bflo(u) * w;
            float pHi = bfhi(u) * w;
            int sel = (k >= b1) + (k >= b2) + (k >= b3);
            aLo[0] += (sel == 0) ? pLo : 0.f;  aHi[0] += (sel == 0) ? pHi : 0.f;
            aLo[1] += (sel == 1) ? pLo : 0.f;  aHi[1] += (sel == 1) ? pHi : 0.f;
            aLo[2] += (sel == 2) ? pLo : 0.f;  aHi[2] += (sel == 2) ? pHi : 0.f;
            aLo[3] += (sel == 3) ? pLo : 0.f;  aHi[3] += (sel == 3) ? pHi : 0.f;
        }
    }
}

// ---- fused: layer-1 aggregate (+bias1, relu) THEN layer-2 gemm (@W2) ----
// r5-identical (needs full rows for the GEMM; not feature-split).

__global__ __launch_bounds__(256) void agg_gemm(const __hip_bfloat16* __restrict__ Hbf,
                                                const int* __restrict__ off,
                                                const unsigned int* __restrict__ edges,
                                                const float* __restrict__ inv_sqrt,
                                                const float* __restrict__ invdeg,
                                                const float* __restrict__ bias,
                                                const float* __restrict__ W2,
                                                __hip_bfloat16* __restrict__ Ybf2) {
    __shared__ float Ws[64 * 64];
    __shared__ float rowbuf[4][4][64];   // [wave][r][j]
    for (int i = threadIdx.x; i < 64 * 64; i += 256) Ws[i] = W2[i];
    __syncthreads();
    const unsigned int* H2 = (const unsigned int*)Hbf;
    int wave = threadIdx.x >> 6;
    int j    = threadIdx.x & 63;
    int m = j & 31, h = j >> 5;
    int n0   = (blockIdx.x * 4 + wave) * 4;   // N_NODES = 16*3125: exact
    int e0 = off[n0], b1v = off[n0 + 1], b2v = off[n0 + 2], b3v = off[n0 + 3], e4 = off[n0 + 4];
    float aLo[4] = {0.f, 0.f, 0.f, 0.f};
    float aHi[4] = {0.f, 0.f, 0.f, 0.f};
    gather4_packed(H2, edges, e0, b1v, b2v, b3v, e4, m, h, aLo, aHi);
    float bLo = bias[2 * m], bHi = bias[2 * m + 1];
#pragma unroll
    for (int r = 0; r < 4; ++r) {
        aLo[r] += __shfl_xor(aLo[r], 32);
        aHi[r] += __shfl_xor(aHi[r], 32);
        float isq = inv_sqrt[n0 + r];
        aLo[r] *= isq;
        aHi[r] *= isq;
        unsigned int u = H2[(size_t)(n0 + r) * 32 + m];   // self row
        float iv = invdeg[n0 + r];
        float vLo = fmaf(bflo(u), iv, aLo[r]) + bLo;
        float vHi = fmaf(bfhi(u), iv, aHi[r]) + bHi;
        if (h == 0) {
            rowbuf[wave][r][2 * m]     = fmaxf(vLo, 0.f);
            rowbuf[wave][r][2 * m + 1] = fmaxf(vHi, 0.f);
        }
    }
    // same-wave LDS write->read: compiler inserts lgkmcnt wait; no barrier needed
    float acc2[4] = {0.f, 0.f, 0.f, 0.f};
#pragma unroll
    for (int k4 = 0; k4 < 16; ++k4) {
        float w0 = Ws[(4 * k4 + 0) * 64 + j];
        float w1 = Ws[(4 * k4 + 1) * 64 + j];
        float w2 = Ws[(4 * k4 + 2) * 64 + j];
        float w3 = Ws[(4 * k4 + 3) * 64 + j];
#pragma unroll
        for (int r = 0; r < 4; ++r) {
            float4 h4 = *(const float4*)&rowbuf[wave][r][k4 * 4];  // broadcast: free
            acc2[r] = fmaf(h4.x, w0, acc2[r]);
            acc2[r] = fmaf(h4.y, w1, acc2[r]);
            acc2[r] = fmaf(h4.z, w2, acc2[r]);
            acc2[r] = fmaf(h4.w, w3, acc2[r]);
        }
    }
#pragma unroll
    for (int r = 0; r < 4; ++r)
        Ybf2[(size_t)(n0 + r) * DIM + j] = __float2bfloat16(acc2[r]);
}

// ---- layer-2 aggregate (+bias2, relu) + mean-pool, FEATURE-SPLIT by XCD ----
// blockIdx&7 -> XCD (round-robin heuristic): XCDs 0-3 handle feature uints
// [0,16), XCDs 4-7 handle [16,32). Per-XCD gather hot set = 3.2MB < 4MB L2.
// Pool output is feature-separable so halves never interact. Mapping is
// perf-only: any (tile, half) computes correctly on any XCD.

__global__ __launch_bounds__(256) void agg_pool(const __hip_bfloat16* __restrict__ Hbf,
                                                const int* __restrict__ off,
                                                const unsigned int* __restrict__ edges,
                                                const float* __restrict__ inv_sqrt,
                                                const float* __restrict__ invdeg,
                                                const float* __restrict__ bias,
                                                const int* __restrict__ batch,
                                                float* __restrict__ sums) {
    int x  = blockIdx.x & 7;
    int fh = x >> 2;                           // feature half
    int t  = (blockIdx.x >> 3) * 4 + (x & 3);  // tile
    if (t >= AGG_TILES) return;
    const unsigned int* H2 = (const unsigned int*)Hbf;
    int wave = threadIdx.x >> 6;
    int j    = threadIdx.x & 63;
    int m = j & 15, h = j >> 4;
    int mm = fh * 16 + m;
    int n0   = (t * 4 + wave) * 4;
    int e0 = off[n0], b1v = off[n0 + 1], b2v = off[n0 + 2], b3v = off[n0 + 3], e4 = off[n0 + 4];
    float aLo[4] = {0.f, 0.f, 0.f, 0.f};
    float aHi[4] = {0.f, 0.f, 0.f, 0.f};
    gatherQ(H2, edges, e0, b1v, b2v, b3v, e4, mm, h, aLo, aHi);
    float bLo = bias[2 * mm], bHi = bias[2 * mm + 1];
    float vLo[4], vHi[4];
#pragma unroll
    for (int r = 0; r < 4; ++r) {
        aLo[r] += __shfl_xor(aLo[r], 16);      // combine the 4 h-groups
        aLo[r] += __shfl_xor(aLo[r], 32);
        aHi[r] += __shfl_xor(aHi[r], 16);
        aHi[r] += __shfl_xor(aHi[r], 32);
        float isq = inv_sqrt[n0 + r];
        aLo[r] *= isq;
        aHi[r] *= isq;
        unsigned int u = H2[(size_t)(n0 + r) * 32 + mm];
        float iv = invdeg[n0 + r];
        vLo[r] = fmaxf(fmaf(bflo(u), iv, aLo[r]) + bLo, 0.f);
        vHi[r] = fmaxf(fmaf(bfhi(u), iv, aHi[r]) + bHi, 0.f);
    }
    if (h == 0) {                              // 16 lanes x 2 feats = this half
        int g0 = batch[n0], g3 = batch[n0 + 3];
        if (g0 == g3) {
            atomicAdd(&sums[g0 * DIM + 2 * mm],     (vLo[0] + vLo[1]) + (vLo[2] + vLo[3]));
            atomicAdd(&sums[g0 * DIM + 2 * mm + 1], (vHi[0] + vHi[1]) + (vHi[2] + vHi[3]));
        } else {
#pragma unroll
            for (int r = 0; r < 4; ++r) {
                int g = batch[n0 + r];
                atomicAdd(&sums[g * DIM + 2 * mm],     vLo[r]);
                atomicAdd(&sums[g * DIM + 2 * mm + 1], vHi[r]);
            }
        }
    }
}

// ---- FC over pooled means: one 64-thread block per graph ----

__global__ __launch_bounds__(64) void fc(const float* __restrict__ sums,
                                         const int* __restrict__ batch,
                                         const float* __restrict__ fcW,
                                         const float* __restrict__ fcb,
                                         float* __restrict__ out) {
    __shared__ float mean[64];
    int g = blockIdx.x;
    int lo = 0, hi = N_NODES;
    while (lo < hi) { int mid = (lo + hi) >> 1; if (batch[mid] < g) lo = mid + 1; else hi = mid; }
    int start = lo;
    hi = N_NODES;
    while (lo < hi) { int mid = (lo + hi) >> 1; if (batch[mid] < g + 1) lo = mid + 1; else hi = mid; }
    int end = lo;
    float inv = 1.0f / fmaxf((float)(end - start), 1.0f);
    mean[threadIdx.x] = sums[g * DIM + threadIdx.x] * inv;   // same-wave LDS, no barrier
    if (threadIdx.x < ODIM) {
        int jj = threadIdx.x;
        float a = fcb[jj];
#pragma unroll
        for (int k = 0; k < DIM; ++k) a = fmaf(mean[k], fcW[k * ODIM + jj], a);
        out[g * ODIM + jj] = a;
    }
}

extern "C" void kernel_launch(void* const* d_in, const int* in_sizes, int n_in,
                              void* d_out, int out_size, void* d_ws, size_t ws_size,
                              hipStream_t stream) {
    const float* x    = (const float*)d_in[0];
    const float* W1   = (const float*)d_in[1];
    const float* b1   = (const float*)d_in[2];
    const float* W2   = (const float*)d_in[3];
    const float* b2   = (const float*)d_in[4];
    const float* fcW  = (const float*)d_in[5];
    const float* fcb  = (const float*)d_in[6];
    const int*   eidx = (const int*)d_in[7];
    const int*   batch= (const int*)d_in[8];
    const int* esrc = eidx;
    const int* edst = eidx + N_EDGES;
    float* out = (float*)d_out;

    char* ws = (char*)d_ws;
    size_t o = 0;
    auto alloc = [&](size_t bytes) {
        void* p = ws + o;
        o += (bytes + 255) & ~(size_t)255;
        return p;
    };
    float* sums     = (float*)alloc((size_t)N_GRAPHS * DIM * 4);   // zeroed by colscan block 0
    __hip_bfloat16* bf1 = (__hip_bfloat16*)alloc((size_t)N_NODES * DIM * 2);
    __hip_bfloat16* bf2 = (__hip_bfloat16*)alloc((size_t)N_NODES * DIM * 2);
    int*   deg      = (int*)  alloc((size_t)N_NODES * 4);
    int*   off      = (int*)  alloc((size_t)(N_NODES + 1) * 4);
    float* inv_sqrt = (float*)alloc((size_t)N_NODES * 4);
    float* invdeg   = (float*)alloc((size_t)N_NODES * 4);
    unsigned short* rank = (unsigned short*)alloc((size_t)N_EDGES * 2);
    unsigned int* edges = (unsigned int*)alloc((size_t)N_EDGES * 4);
    unsigned int* cnt_blocks = (unsigned int*)alloc((size_t)NHB * HCOLS * 4);  // 12.5MB
    unsigned int* blockbase  = (unsigned int*)alloc((size_t)NHB * HCOLS * 4);  // 12.5MB
    int*   blocksum = (int*)  alloc((size_t)SCAN_NB2 * 4);

    prep_gemm<<<NHB + GEMM_BLOCKS, 256, 0, stream>>>(edst, rank, cnt_blocks, x, W1, bf1);
    colscan<<<SCAN_NB2, 256, 0, stream>>>(cnt_blocks, blockbase, deg, blocksum, sums);
    scan_p3<<<SCAN_NB2, 256, 0, stream>>>(deg, blocksum, off, inv_sqrt, invdeg);
    scatter_edges<<<EDGE_BLOCKS, 256, 0, stream>>>(esrc, edst, rank, off, blockbase, inv_sqrt, edges);

    agg_gemm<<<AGG_TILES, 256, 0, stream>>>(bf1, off, edges, inv_sqrt, invdeg, b1, W2, bf2);
    agg_pool<<<POOL_BLOCKS, 256, 0, stream>>>(bf2, off, edges, inv_sqrt, invdeg, b2, batch, sums);

    fc<<<N_GRAPHS, 64, 0, stream>>>(sums, batch, fcW, fcb, out);
}

// Round 11
// 214.273 us; speedup vs baseline: 4.4951x; 1.0342x over previous
//
#include <hip/hip_runtime.h>
#include <hip/hip_bf16.h>
#include <hip/hip_fp16.h>

#define N_NODES 50000
#define N_EDGES 800000
#define DIM 64
#define ODIM 32
#define N_GRAPHS 512
#define GEMM_BLOCKS ((N_NODES + 31) / 32) // 1563
#define EPT 5                             // edges per thread (exact: 800000 = 625*256*5)
#define EDGE_BLOCKS (N_EDGES / (256 * EPT))  // 625
#define EDGE_STRIDE (EDGE_BLOCKS * 256)      // 160000

// LDS counting-sort geometry: 125 edge-chunks x 4 node-ranges.
#define NCH 125
#define CHUNK (N_EDGES / NCH)             // 6400
#define SWEEPS (CHUNK / 256)              // 25
#define UNR 5
#define NR 4
#define NRANGE (N_NODES / NR)             // 12500 nodes per range
#define HCOLS (NRANGE / 2)                // 6250 packed-u32 cols (2 nodes/u32)
#define NHB (NCH * NR)                    // 500 hist blocks
#define NCOLS_TOTAL (NR * HCOLS)          // 25000
#define SCAN_NB2 ((N_NODES + 511) / 512)  // 98 (512 nodes per scan block)

__device__ __forceinline__ float bflo(unsigned int u) { return __uint_as_float(u << 16); }
__device__ __forceinline__ float bfhi(unsigned int u) { return __uint_as_float(u & 0xffff0000u); }
__device__ __forceinline__ float h16tof(unsigned int hbits) {
    return __half2float(__ushort_as_half((unsigned short)hbits));
}

// FINAL: byte-exact r5 restore (best measured: 213.3us).
// Negative-result ledger (all within-session, measured):
//  - persistent kernels + spin barrier (RMW poll):       585us (r6)
//  - persistent kernels + read-poll barrier:             724us (r7)
//  - last-block pattern (1 acq-rel RMW per block):       963us (r8)
//  - nt hints on edge/store streams:                     223us (r9)
//  - feature-split pool (per-XCD L2 partitioning):       222us (r10)
// Conclusion: aggs are latency-bound at what the cache hierarchy delivers;
// dispatch-chain overhead can't be removed without device-scope sync, which
// this chip punishes 10-100x. ~213us is the practical floor here.

// ---- fused: LDS-histogram count (zero global atomics) + layer-1 GEMM ----

__global__ __launch_bounds__(256) void prep_gemm(const int* __restrict__ dst,
                                                 unsigned short* __restrict__ rank,
                                                 unsigned int* __restrict__ cnt_blocks,
                                                 const float* __restrict__ X,
                                                 const float* __restrict__ W,
                                                 __hip_bfloat16* __restrict__ Ybf) {
    __shared__ unsigned int smem[HCOLS];   // 25KB; GEMM reuses as float Ws[4096] (16KB)
    if (blockIdx.x < NHB) {
        unsigned int* hist = smem;
        int c = blockIdx.x >> 2, r = blockIdx.x & 3;
        for (int i = threadIdx.x; i < HCOLS; i += 256) hist[i] = 0;
        __syncthreads();
        int lo = r * NRANGE;
        int base = c * CHUNK + threadIdx.x;
#pragma unroll 1
        for (int b = 0; b < SWEEPS / UNR; ++b) {
            int d[UNR];
#pragma unroll
            for (int u = 0; u < UNR; ++u)                 // 5 loads in flight
                d[u] = dst[base + (b * UNR + u) * 256];
#pragma unroll
            for (int u = 0; u < UNR; ++u) {
                unsigned int ld = (unsigned int)(d[u] - lo);
                if (ld < (unsigned int)NRANGE) {
                    unsigned int sh = (ld & 1u) * 16u;
                    unsigned int ret = atomicAdd(&hist[ld >> 1], 1u << sh);
                    rank[base + (b * UNR + u) * 256] = (unsigned short)((ret >> sh) & 0xffffu);
                }
            }
        }
        __syncthreads();
        unsigned int* out = cnt_blocks + (size_t)blockIdx.x * HCOLS;
        for (int i = threadIdx.x; i < HCOLS; i += 256) out[i] = hist[i];
        return;
    }
    // ---- GEMM part: h = X @ W (N x 64 @ 64 x 64), bf16 out ----
    int bid = blockIdx.x - NHB;
    float* Ws = (float*)smem;
    for (int i = threadIdx.x; i < 64 * 64; i += 256) Ws[i] = W[i];
    __syncthreads();
    int wave = threadIdx.x >> 6;
    int j    = threadIdx.x & 63;
    int row0 = (bid * 4 + wave) * 8;
    if (row0 >= N_NODES) return;
    float acc[8] = {0,0,0,0,0,0,0,0};
    const float* x0 = X + (size_t)row0 * DIM;   // wave-uniform
    int nr = (row0 + 8 <= N_NODES) ? 8 : (N_NODES - row0);
    if (nr == 8) {
#pragma unroll
        for (int k4 = 0; k4 < 16; ++k4) {
            float w0 = Ws[(4 * k4 + 0) * 64 + j];
            float w1 = Ws[(4 * k4 + 1) * 64 + j];
            float w2 = Ws[(4 * k4 + 2) * 64 + j];
            float w3 = Ws[(4 * k4 + 3) * 64 + j];
#pragma unroll
            for (int r = 0; r < 8; ++r) {
                float4 x4 = *(const float4*)&x0[r * DIM + k4 * 4];
                acc[r] = fmaf(x4.x, w0, acc[r]);
                acc[r] = fmaf(x4.y, w1, acc[r]);
                acc[r] = fmaf(x4.z, w2, acc[r]);
                acc[r] = fmaf(x4.w, w3, acc[r]);
            }
        }
    } else {
        for (int k4 = 0; k4 < 16; ++k4) {
            float w0 = Ws[(4 * k4 + 0) * 64 + j];
            float w1 = Ws[(4 * k4 + 1) * 64 + j];
            float w2 = Ws[(4 * k4 + 2) * 64 + j];
            float w3 = Ws[(4 * k4 + 3) * 64 + j];
            for (int r = 0; r < nr; ++r) {
                float4 x4 = *(const float4*)&x0[r * DIM + k4 * 4];
                acc[r] = fmaf(x4.x, w0, acc[r]);
                acc[r] = fmaf(x4.y, w1, acc[r]);
                acc[r] = fmaf(x4.z, w2, acc[r]);
                acc[r] = fmaf(x4.w, w3, acc[r]);
            }
        }
    }
    for (int r = 0; r < nr; ++r)
        Ybf[(size_t)(row0 + r) * DIM + j] = __float2bfloat16(acc[r]);
}

// ---- column scan + (fused) block-sum reduction + sums zeroing ----
// Thread q owns nodes {2q, 2q+1}: r=q/HCOLS, col=q%HCOLS (node-ordered).
// Iterates its 125 chunk histograms (packed u32 adds safe: deg < 2^16).
// Block b covers nodes [512b, 512b+512) -> blocksum[b] feeds scan_p3 directly
// (replaces the scan_p1 dispatch). Block 0 also zeroes sums[] (replaces memset).

__global__ __launch_bounds__(256) void colscan(const unsigned int* __restrict__ cnt_blocks,
                                               unsigned int* __restrict__ blockbase,
                                               int* __restrict__ deg,
                                               int* __restrict__ blocksum,
                                               float* __restrict__ sums) {
    __shared__ int ws[4];
    int q = blockIdx.x * 256 + threadIdx.x;
    int d0 = 0, d1 = 0;
    if (q < NCOLS_TOTAL) {
        int r = q / HCOLS, col = q % HCOLS;
        unsigned int run = 0;
#pragma unroll 5
        for (int c = 0; c < NCH; ++c) {
            size_t idx = (size_t)(c * NR + r) * HCOLS + col;
            unsigned int v = cnt_blocks[idx];
            blockbase[idx] = run;      // exclusive prefix (packed u16x2)
            run += v;
        }
        d0 = (int)(run & 0xffffu);
        d1 = (int)(run >> 16);
        deg[2 * q]     = d0;
        deg[2 * q + 1] = d1;
    }
    int v = d0 + d1;
    for (int d = 32; d > 0; d >>= 1) v += __shfl_down(v, d, 64);
    int lane = threadIdx.x & 63, wid = threadIdx.x >> 6;
    if (lane == 0) ws[wid] = v;
    __syncthreads();
    if (threadIdx.x == 0) blocksum[blockIdx.x] = ws[0] + ws[1] + ws[2] + ws[3];
    if (blockIdx.x == 0)
        for (int i = threadIdx.x; i < N_GRAPHS * DIM; i += 256) sums[i] = 0.f;
}

// ---- final scan: 512 nodes/block (2/thread), same geometry as colscan ----

__global__ __launch_bounds__(256) void scan_p3(const int* __restrict__ deg,
                                               const int* __restrict__ blocksum,
                                               int* __restrict__ off,
                                               float* __restrict__ inv_sqrt,
                                               float* __restrict__ invdeg) {
    __shared__ int wtot[4];
    __shared__ int bb[SCAN_NB2 + 1];
    {
        int t = threadIdx.x;
        int v = (t < SCAN_NB2) ? blocksum[t] : 0;
        int lane = t & 63, wid = t >> 6;
        int incl = v;
        for (int d = 1; d < 64; d <<= 1) {
            int u = __shfl_up(incl, d, 64);
            if (lane >= d) incl += u;
        }
        if (lane == 63) wtot[wid] = incl;
        __syncthreads();
        int base = 0;
        for (int w = 0; w < wid; ++w) base += wtot[w];
        incl += base;
        if (t <= SCAN_NB2) bb[t] = incl - v;   // exclusive; bb[SCAN_NB2] = total
        __syncthreads();
    }
    if (blockIdx.x == 0 && threadIdx.x == 0) off[N_NODES] = bb[SCAN_NB2];
    __syncthreads();

    int n = blockIdx.x * 512 + 2 * threadIdx.x;
    int d0 = 0, d1 = 0;
    if (n < N_NODES) { int2 dd = *(const int2*)&deg[n]; d0 = dd.x; d1 = dd.y; }
    int v = d0 + d1;
    int lane = threadIdx.x & 63, wid = threadIdx.x >> 6;
    int incl = v;
    for (int d = 1; d < 64; d <<= 1) {
        int u = __shfl_up(incl, d, 64);
        if (lane >= d) incl += u;
    }
    if (lane == 63) wtot[wid] = incl;
    __syncthreads();
    int base = bb[blockIdx.x];
    for (int w = 0; w < wid; ++w) base += wtot[w];
    int excl = base + incl - v;
    if (n < N_NODES) {
        off[n]     = excl;
        off[n + 1] = excl + d0;
        float f0 = (float)(d0 + 1), f1 = (float)(d1 + 1);   // +1: self-loop
        inv_sqrt[n]     = rsqrtf(f0);
        inv_sqrt[n + 1] = rsqrtf(f1);
        invdeg[n]       = 1.0f / f0;
        invdeg[n + 1]   = 1.0f / f1;
    }
}

// ---- atomic-free scatter: pos = off[d] + blockbase(chunk,d) + rank ----
// Edge record: src (u16) | half(inv_sqrt[src]) << 16. The dst-side isq factor
// is applied once per node in the agg kernels (Σ isq_s·isq_d·h = isq_d·Σ isq_s·h),
// which drops the per-edge inv_sqrt[d] gather here.

__global__ __launch_bounds__(256) void scatter_edges(const int* __restrict__ src,
                                                     const int* __restrict__ dst,
                                                     const unsigned short* __restrict__ rank,
                                                     const int* __restrict__ off,
                                                     const unsigned int* __restrict__ blockbase,
                                                     const float* __restrict__ inv_sqrt,
                                                     unsigned int* __restrict__ edges) {
    int t = blockIdx.x * 256 + threadIdx.x;
    int d[EPT], s[EPT];
    unsigned short rk[EPT];
#pragma unroll
    for (int i = 0; i < EPT; ++i) d[i] = dst[t + i * EDGE_STRIDE];
#pragma unroll
    for (int i = 0; i < EPT; ++i) s[i] = src[t + i * EDGE_STRIDE];
#pragma unroll
    for (int i = 0; i < EPT; ++i) rk[i] = rank[t + i * EDGE_STRIDE];
    int pos[EPT];
    float w[EPT];
#pragma unroll
    for (int i = 0; i < EPT; ++i) {
        int e = t + i * EDGE_STRIDE;
        int c = e / CHUNK;
        int r = d[i] / NRANGE;
        int ld = d[i] - r * NRANGE;
        unsigned int bb = blockbase[(size_t)(c * NR + r) * HCOLS + (ld >> 1)];
        int base16 = (int)((bb >> ((ld & 1) * 16)) & 0xffffu);
        pos[i] = off[d[i]] + base16 + (int)rk[i];
    }
#pragma unroll
    for (int i = 0; i < EPT; ++i) w[i] = inv_sqrt[s[i]];
#pragma unroll
    for (int i = 0; i < EPT; ++i) {
        unsigned short hw = __half_as_ushort(__float2half(w[i]));
        edges[pos[i]] = (unsigned int)s[i] | ((unsigned int)hw << 16);
    }
}

// ---- half-wave packed merged-stream gather for 4 consecutive nodes ----
// Depth-3 pipeline: gathers for batches b+1,b+2 and edge loads for b+3 stay
// in flight across consume(b).
__device__ __forceinline__ void gather4_packed(
    const unsigned int* __restrict__ H2,
    const unsigned int* __restrict__ edges,
    int e0, int b1, int b2, int b3, int e4, int m, int h,
    float (&aLo)[4], float (&aHi)[4])
{
    int k = e0;
    int B = (e4 - e0) >> 3;

    unsigned int E0[4], E1[4], E2[4];
    unsigned int U0[4], U1[4];

    auto ld4 = [&](unsigned int* E, int kb) {
#pragma unroll
        for (int i = 0; i < 4; ++i) E[i] = edges[kb + 2 * i + h];
    };
    auto gt4 = [&](unsigned int* U, const unsigned int* E) {
#pragma unroll
        for (int i = 0; i < 4; ++i)
            U[i] = H2[(size_t)(E[i] & 0xffffu) * 32 + m];
    };
    auto consume = [&](const unsigned int* E, const unsigned int* U, int kb) {
        int selA = (kb >= b1) + (kb >= b2) + (kb >= b3);
        int selB = (kb + 7 >= b1) + (kb + 7 >= b2) + (kb + 7 >= b3);
        if (selA == selB) {                 // whole batch in one node (common)
            float sLo = 0.f, sHi = 0.f;
#pragma unroll
            for (int i = 0; i < 4; ++i) {
                float w = h16tof(E[i] >> 16);
                sLo = fmaf(bflo(U[i]), w, sLo);
                sHi = fmaf(bfhi(U[i]), w, sHi);
            }
            if      (selA == 0) { aLo[0] += sLo; aHi[0] += sHi; }
            else if (selA == 1) { aLo[1] += sLo; aHi[1] += sHi; }
            else if (selA == 2) { aLo[2] += sLo; aHi[2] += sHi; }
            else                { aLo[3] += sLo; aHi[3] += sHi; }
        } else {                            // boundary batch: per-edge select
#pragma unroll
            for (int i = 0; i < 4; ++i) {
                int kk = kb + 2 * i + h;
                float w = h16tof(E[i] >> 16);
                float pLo = bflo(U[i]) * w;
                float pHi = bfhi(U[i]) * w;
                int sel = (kk >= b1) + (kk >= b2) + (kk >= b3);
                aLo[0] += (sel == 0) ? pLo : 0.f;  aHi[0] += (sel == 0) ? pHi : 0.f;
                aLo[1] += (sel == 1) ? pLo : 0.f;  aHi[1] += (sel == 1) ? pHi : 0.f;
                aLo[2] += (sel == 2) ? pLo : 0.f;  aHi[2] += (sel == 2) ? pHi : 0.f;
                aLo[3] += (sel == 3) ? pLo : 0.f;  aHi[3] += (sel == 3) ? pHi : 0.f;
            }
        }
    };

    if (B >= 3) {
        ld4(E0, k);      gt4(U0, E0);
        ld4(E1, k + 8);  gt4(U1, E1);
        ld4(E2, k + 16);
        for (int b = 0; b < B - 3; ++b) {
            unsigned int U2[4];
            gt4(U2, E2);              // batch b+2 gathers in flight
            unsigned int E3[4];
            ld4(E3, k + 24);          // batch b+3 edge loads in flight
            consume(E0, U0, k);       // waits only on batch b gathers
#pragma unroll
            for (int i = 0; i < 4; ++i) {
                E0[i] = E1[i]; U0[i] = U1[i];
                E1[i] = E2[i]; U1[i] = U2[i];
                E2[i] = E3[i];
            }
            k += 8;
        }
        {
            unsigned int U2[4];
            gt4(U2, E2);
            consume(E0, U0, k); k += 8;
            consume(E1, U1, k); k += 8;
            consume(E2, U2, k); k += 8;
        }
    } else if (B == 2) {
        ld4(E0, k);     gt4(U0, E0);
        ld4(E1, k + 8); gt4(U1, E1);
        consume(E0, U0, k); k += 8;
        consume(E1, U1, k); k += 8;
    } else if (B == 1) {
        ld4(E0, k); gt4(U0, E0); consume(E0, U0, k); k += 8;
    }
    for (; k < e4; ++k) {
        if ((k & 1) == h) {       // split tail edges between halves
            unsigned int e = edges[k];
            unsigned int u = H2[(size_t)(e & 0xffffu) * 32 + m];
            float w = h16tof(e >> 16);
            float pLo = bflo(u) * w;
            float pHi = bfhi(u) * w;
            int sel = (k >= b1) + (k >= b2) + (k >= b3);
            aLo[0] += (sel == 0) ? pLo : 0.f;  aHi[0] += (sel == 0) ? pHi : 0.f;
            aLo[1] += (sel == 1) ? pLo : 0.f;  aHi[1] += (sel == 1) ? pHi : 0.f;
            aLo[2] += (sel == 2) ? pLo : 0.f;  aHi[2] += (sel == 2) ? pHi : 0.f;
            aLo[3] += (sel == 3) ? pLo : 0.f;  aHi[3] += (sel == 3) ? pHi : 0.f;
        }
    }
}

// ---- fused: layer-1 aggregate (+bias1, relu) THEN layer-2 gemm (@W2) ----
// Edge weights carry isq_src only; isq_dst applied once per node here.

__global__ __launch_bounds__(256) void agg_gemm(const __hip_bfloat16* __restrict__ Hbf,
                                                const int* __restrict__ off,
                                                const unsigned int* __restrict__ edges,
                                                const float* __restrict__ inv_sqrt,
                                                const float* __restrict__ invdeg,
                                                const float* __restrict__ bias,
                                                const float* __restrict__ W2,
                                                __hip_bfloat16* __restrict__ Ybf2) {
    __shared__ float Ws[64 * 64];
    __shared__ float rowbuf[4][4][64];   // [wave][r][j]
    for (int i = threadIdx.x; i < 64 * 64; i += 256) Ws[i] = W2[i];
    __syncthreads();
    const unsigned int* H2 = (const unsigned int*)Hbf;
    int wave = threadIdx.x >> 6;
    int j    = threadIdx.x & 63;
    int m = j & 31, h = j >> 5;
    int n0   = (blockIdx.x * 4 + wave) * 4;   // N_NODES = 16*3125: exact
    int e0 = off[n0], b1v = off[n0 + 1], b2v = off[n0 + 2], b3v = off[n0 + 3], e4 = off[n0 + 4];
    float aLo[4] = {0.f, 0.f, 0.f, 0.f};
    float aHi[4] = {0.f, 0.f, 0.f, 0.f};
    gather4_packed(H2, edges, e0, b1v, b2v, b3v, e4, m, h, aLo, aHi);
    float bLo = bias[2 * m], bHi = bias[2 * m + 1];
#pragma unroll
    for (int r = 0; r < 4; ++r) {
        aLo[r] += __shfl_xor(aLo[r], 32);
        aHi[r] += __shfl_xor(aHi[r], 32);
        float isq = inv_sqrt[n0 + r];
        aLo[r] *= isq;
        aHi[r] *= isq;
        unsigned int u = H2[(size_t)(n0 + r) * 32 + m];   // self row
        float iv = invdeg[n0 + r];
        float vLo = fmaf(bflo(u), iv, aLo[r]) + bLo;
        float vHi = fmaf(bfhi(u), iv, aHi[r]) + bHi;
        if (h == 0) {
            rowbuf[wave][r][2 * m]     = fmaxf(vLo, 0.f);
            rowbuf[wave][r][2 * m + 1] = fmaxf(vHi, 0.f);
        }
    }
    // same-wave LDS write->read: compiler inserts lgkmcnt wait; no barrier needed
    float acc2[4] = {0.f, 0.f, 0.f, 0.f};
#pragma unroll
    for (int k4 = 0; k4 < 16; ++k4) {
        float w0 = Ws[(4 * k4 + 0) * 64 + j];
        float w1 = Ws[(4 * k4 + 1) * 64 + j];
        float w2 = Ws[(4 * k4 + 2) * 64 + j];
        float w3 = Ws[(4 * k4 + 3) * 64 + j];
#pragma unroll
        for (int r = 0; r < 4; ++r) {
            float4 h4 = *(const float4*)&rowbuf[wave][r][k4 * 4];  // broadcast: free
            acc2[r] = fmaf(h4.x, w0, acc2[r]);
            acc2[r] = fmaf(h4.y, w1, acc2[r]);
            acc2[r] = fmaf(h4.z, w2, acc2[r]);
            acc2[r] = fmaf(h4.w, w3, acc2[r]);
        }
    }
#pragma unroll
    for (int r = 0; r < 4; ++r)
        Ybf2[(size_t)(n0 + r) * DIM + j] = __float2bfloat16(acc2[r]);
}

// ---- layer-2 aggregate (+bias2, relu) fused with mean-pool accumulation ----

__global__ __launch_bounds__(256) void agg_pool(const __hip_bfloat16* __restrict__ Hbf,
                                                const int* __restrict__ off,
                                                const unsigned int* __restrict__ edges,
                                                const float* __restrict__ inv_sqrt,
                                                const float* __restrict__ invdeg,
                                                const float* __restrict__ bias,
                                                const int* __restrict__ batch,
                                                float* __restrict__ sums) {
    const unsigned int* H2 = (const unsigned int*)Hbf;
    int wave = threadIdx.x >> 6;
    int j    = threadIdx.x & 63;
    int m = j & 31, h = j >> 5;
    int n0   = (blockIdx.x * 4 + wave) * 4;   // exact
    int e0 = off[n0], b1v = off[n0 + 1], b2v = off[n0 + 2], b3v = off[n0 + 3], e4 = off[n0 + 4];
    float aLo[4] = {0.f, 0.f, 0.f, 0.f};
    float aHi[4] = {0.f, 0.f, 0.f, 0.f};
    gather4_packed(H2, edges, e0, b1v, b2v, b3v, e4, m, h, aLo, aHi);
    float bLo = bias[2 * m], bHi = bias[2 * m + 1];
    float vLo[4], vHi[4];
#pragma unroll
    for (int r = 0; r < 4; ++r) {
        aLo[r] += __shfl_xor(aLo[r], 32);
        aHi[r] += __shfl_xor(aHi[r], 32);
        float isq = inv_sqrt[n0 + r];
        aLo[r] *= isq;
        aHi[r] *= isq;
        unsigned int u = H2[(size_t)(n0 + r) * 32 + m];
        float iv = invdeg[n0 + r];
        vLo[r] = fmaxf(fmaf(bflo(u), iv, aLo[r]) + bLo, 0.f);
        vHi[r] = fmaxf(fmaf(bfhi(u), iv, aHi[r]) + bHi, 0.f);
    }
    if (h == 0) {
        int g0 = batch[n0], g3 = batch[n0 + 3];
        if (g0 == g3) {
            atomicAdd(&sums[g0 * DIM + 2 * m],     (vLo[0] + vLo[1]) + (vLo[2] + vLo[3]));
            atomicAdd(&sums[g0 * DIM + 2 * m + 1], (vHi[0] + vHi[1]) + (vHi[2] + vHi[3]));
        } else {
#pragma unroll
            for (int r = 0; r < 4; ++r) {
                int g = batch[n0 + r];
                atomicAdd(&sums[g * DIM + 2 * m],     vLo[r]);
                atomicAdd(&sums[g * DIM + 2 * m + 1], vHi[r]);
            }
        }
    }
}

// ---- FC over pooled means: one 64-thread block per graph ----

__global__ __launch_bounds__(64) void fc(const float* __restrict__ sums,
                                         const int* __restrict__ batch,
                                         const float* __restrict__ fcW,
                                         const float* __restrict__ fcb,
                                         float* __restrict__ out) {
    __shared__ float mean[64];
    int g = blockIdx.x;
    int lo = 0, hi = N_NODES;
    while (lo < hi) { int mid = (lo + hi) >> 1; if (batch[mid] < g) lo = mid + 1; else hi = mid; }
    int start = lo;
    hi = N_NODES;
    while (lo < hi) { int mid = (lo + hi) >> 1; if (batch[mid] < g + 1) lo = mid + 1; else hi = mid; }
    int end = lo;
    float inv = 1.0f / fmaxf((float)(end - start), 1.0f);
    mean[threadIdx.x] = sums[g * DIM + threadIdx.x] * inv;   // same-wave LDS, no barrier
    if (threadIdx.x < ODIM) {
        int jj = threadIdx.x;
        float a = fcb[jj];
#pragma unroll
        for (int k = 0; k < DIM; ++k) a = fmaf(mean[k], fcW[k * ODIM + jj], a);
        out[g * ODIM + jj] = a;
    }
}

extern "C" void kernel_launch(void* const* d_in, const int* in_sizes, int n_in,
                              void* d_out, int out_size, void* d_ws, size_t ws_size,
                              hipStream_t stream) {
    const float* x    = (const float*)d_in[0];
    const float* W1   = (const float*)d_in[1];
    const float* b1   = (const float*)d_in[2];
    const float* W2   = (const float*)d_in[3];
    const float* b2   = (const float*)d_in[4];
    const float* fcW  = (const float*)d_in[5];
    const float* fcb  = (const float*)d_in[6];
    const int*   eidx = (const int*)d_in[7];
    const int*   batch= (const int*)d_in[8];
    const int* esrc = eidx;
    const int* edst = eidx + N_EDGES;
    float* out = (float*)d_out;

    char* ws = (char*)d_ws;
    size_t o = 0;
    auto alloc = [&](size_t bytes) {
        void* p = ws + o;
        o += (bytes + 255) & ~(size_t)255;
        return p;
    };
    float* sums     = (float*)alloc((size_t)N_GRAPHS * DIM * 4);   // zeroed by colscan block 0
    __hip_bfloat16* bf1 = (__hip_bfloat16*)alloc((size_t)N_NODES * DIM * 2);
    __hip_bfloat16* bf2 = (__hip_bfloat16*)alloc((size_t)N_NODES * DIM * 2);
    int*   deg      = (int*)  alloc((size_t)N_NODES * 4);
    int*   off      = (int*)  alloc((size_t)(N_NODES + 1) * 4);
    float* inv_sqrt = (float*)alloc((size_t)N_NODES * 4);
    float* invdeg   = (float*)alloc((size_t)N_NODES * 4);
    unsigned short* rank = (unsigned short*)alloc((size_t)N_EDGES * 2);
    unsigned int* edges = (unsigned int*)alloc((size_t)N_EDGES * 4);
    unsigned int* cnt_blocks = (unsigned int*)alloc((size_t)NHB * HCOLS * 4);  // 12.5MB
    unsigned int* blockbase  = (unsigned int*)alloc((size_t)NHB * HCOLS * 4);  // 12.5MB
    int*   blocksum = (int*)  alloc((size_t)SCAN_NB2 * 4);

    prep_gemm<<<NHB + GEMM_BLOCKS, 256, 0, stream>>>(edst, rank, cnt_blocks, x, W1, bf1);
    colscan<<<SCAN_NB2, 256, 0, stream>>>(cnt_blocks, blockbase, deg, blocksum, sums);
    scan_p3<<<SCAN_NB2, 256, 0, stream>>>(deg, blocksum, off, inv_sqrt, invdeg);
    scatter_edges<<<EDGE_BLOCKS, 256, 0, stream>>>(esrc, edst, rank, off, blockbase, inv_sqrt, edges);

    agg_gemm<<<N_NODES / 16, 256, 0, stream>>>(bf1, off, edges, inv_sqrt, invdeg, b1, W2, bf2);
    agg_pool<<<N_NODES / 16, 256, 0, stream>>>(bf2, off, edges, inv_sqrt, invdeg, b2, batch, sums);

    fc<<<N_GRAPHS, 64, 0, stream>>>(sums, batch, fcW, fcb, out);
}